// Round 3
// baseline (1294.814 us; speedup 1.0000x reference)
//
#include <hip/hip_runtime.h>
#include <cstddef>

#define BB 4
#define SS 2304      // 48*48
#define FF 512
#define NH 8
#define DD 64
#define BSR (BB*SS)  // 9216 rows
#define QR 16        // q-rows per attn block

typedef __attribute__((ext_vector_type(8))) short bf16x8;
typedef __attribute__((ext_vector_type(4))) float f32x4;
#define MFMA16(a,b,c) __builtin_amdgcn_mfma_f32_16x16x32_bf16((a),(b),(c),0,0,0)

__device__ __forceinline__ ushort f2bf_rne(float x) {
    uint u = __float_as_uint(x);
    uint r = u + 0x7fffu + ((u >> 16) & 1u);
    return (ushort)(r >> 16);
}
__device__ __forceinline__ float bfval(ushort h) {
    return __uint_as_float((uint)h << 16);
}

// ---------------------------------------------------------------------------
// Weight transpose+split: W[k][n] (512x512 f32) -> Wt{hi,lo}[n][k] bf16
// ---------------------------------------------------------------------------
__global__ __launch_bounds__(256) void wtsplit_kernel(
    const float* __restrict__ w, ushort* __restrict__ whi, ushort* __restrict__ wlo)
{
    __shared__ __align__(16) float tile[64][68];
    const int t  = threadIdx.x;
    const int kt = blockIdx.x;   // k tile
    const int nt = blockIdx.y;   // n tile
    {
        const int r  = t >> 2;
        const int cg = (t & 3) * 16;
        const float* src = w + (size_t)(kt * 64 + r) * FF + nt * 64 + cg;
        #pragma unroll
        for (int j = 0; j < 4; ++j)
            *(float4*)&tile[r][cg + 4 * j] = *(const float4*)(src + 4 * j);
    }
    __syncthreads();
    {
        const int n  = t >> 2;
        const int kg = (t & 3) * 16;
        union { ushort s[16]; uint4 q[2]; } H, L;
        #pragma unroll
        for (int j = 0; j < 16; ++j) {
            float x = tile[kg + j][n];
            ushort hh = f2bf_rne(x);
            H.s[j] = hh;
            L.s[j] = f2bf_rne(x - bfval(hh));
        }
        size_t off = (size_t)(nt * 64 + n) * FF + kt * 64 + kg;
        *(uint4*)(whi + off)     = H.q[0];
        *(uint4*)(whi + off + 8) = H.q[1];
        *(uint4*)(wlo + off)     = L.q[0];
        *(uint4*)(wlo + off + 8) = L.q[1];
    }
}

// ---------------------------------------------------------------------------
// V transpose+split: v[bh][s][d] f32 -> vt{hi,lo}[bh][d][s] bf16
// ---------------------------------------------------------------------------
__global__ __launch_bounds__(256) void vtsplit_kernel(
    const float* __restrict__ v, ushort* __restrict__ vthi, ushort* __restrict__ vtlo)
{
    __shared__ __align__(16) float tile[64][68];
    const int t  = threadIdx.x;
    const int st = blockIdx.x;
    const int bh = blockIdx.y;
    {
        const int r  = t >> 2;
        const int cg = (t & 3) * 16;
        const float* src = v + ((size_t)bh * SS + st * 64 + r) * DD + cg;
        #pragma unroll
        for (int j = 0; j < 4; ++j)
            *(float4*)&tile[r][cg + 4 * j] = *(const float4*)(src + 4 * j);
    }
    __syncthreads();
    {
        const int d  = t >> 2;
        const int sg = (t & 3) * 16;
        union { ushort s[16]; uint4 q[2]; } H, L;
        #pragma unroll
        for (int j = 0; j < 16; ++j) {
            float x = tile[sg + j][d];
            ushort hh = f2bf_rne(x);
            H.s[j] = hh;
            L.s[j] = f2bf_rne(x - bfval(hh));
        }
        size_t off = ((size_t)bh * DD + d) * SS + st * 64 + sg;
        *(uint4*)(vthi + off)     = H.q[0];
        *(uint4*)(vthi + off + 8) = H.q[1];
        *(uint4*)(vtlo + off)     = L.q[0];
        *(uint4*)(vtlo + off + 8) = L.q[1];
    }
}

// ---------------------------------------------------------------------------
// Projection GEMM via split-bf16 MFMA: out = X @ W + b
// X fp32 [BSR][512] (converted to hi/lo in-register); Wt pre-split [n][k].
// 64x64 tile per block, 256 thr = 4 waves; wave w -> rows i0+16w..+15.
// mode 0: fp32 out[row][512];  mode 1: ushort hi/lo head-split [bh][s][64];
// mode 2: fp32 head-split [bh][s][64]
// ---------------------------------------------------------------------------
__global__ __launch_bounds__(256) void proj_mfma(
    const float* __restrict__ X, const ushort* __restrict__ wth,
    const ushort* __restrict__ wtl, const float* __restrict__ bias,
    float* __restrict__ outf, ushort* __restrict__ outhi,
    ushort* __restrict__ outlo, int mode)
{
    const int t  = threadIdx.x, w = t >> 6, l = t & 63;
    const int ar = l & 15, kg = (l >> 4) * 8;
    const int i0 = blockIdx.x * 64, j0 = blockIdx.y * 64;
    const int arow = i0 + w * 16 + ar;

    f32x4 acc[4];
    #pragma unroll
    for (int nt = 0; nt < 4; ++nt) acc[nt] = (f32x4){0.f, 0.f, 0.f, 0.f};

    for (int kk = 0; kk < FF; kk += 32) {
        const float* xr = X + (size_t)arow * FF + kk + kg;
        float4 f0 = *(const float4*)xr;
        float4 f1 = *(const float4*)(xr + 4);
        float xs0 = f0.x, xs1 = f0.y, xs2 = f0.z, xs3 = f0.w;
        float xs4 = f1.x, xs5 = f1.y, xs6 = f1.z, xs7 = f1.w;
        ushort h0 = f2bf_rne(xs0), h1 = f2bf_rne(xs1), h2 = f2bf_rne(xs2), h3 = f2bf_rne(xs3);
        ushort h4 = f2bf_rne(xs4), h5 = f2bf_rne(xs5), h6 = f2bf_rne(xs6), h7 = f2bf_rne(xs7);
        union { uint u[4]; bf16x8 v; } ah, al;
        ah.u[0] = (uint)h0 | ((uint)h1 << 16);
        ah.u[1] = (uint)h2 | ((uint)h3 << 16);
        ah.u[2] = (uint)h4 | ((uint)h5 << 16);
        ah.u[3] = (uint)h6 | ((uint)h7 << 16);
        al.u[0] = (uint)f2bf_rne(xs0 - bfval(h0)) | ((uint)f2bf_rne(xs1 - bfval(h1)) << 16);
        al.u[1] = (uint)f2bf_rne(xs2 - bfval(h2)) | ((uint)f2bf_rne(xs3 - bfval(h3)) << 16);
        al.u[2] = (uint)f2bf_rne(xs4 - bfval(h4)) | ((uint)f2bf_rne(xs5 - bfval(h5)) << 16);
        al.u[3] = (uint)f2bf_rne(xs6 - bfval(h6)) | ((uint)f2bf_rne(xs7 - bfval(h7)) << 16);
        #pragma unroll
        for (int nt = 0; nt < 4; ++nt) {
            const size_t wo = (size_t)(j0 + nt * 16 + ar) * FF + kk + kg;
            bf16x8 bh = *(const bf16x8*)(wth + wo);
            bf16x8 bl = *(const bf16x8*)(wtl + wo);
            acc[nt] = MFMA16(ah.v, bh, acc[nt]);
            acc[nt] = MFMA16(ah.v, bl, acc[nt]);
            acc[nt] = MFMA16(al.v, bh, acc[nt]);
        }
    }

    const int bidx = i0 / SS;           // 64 | 2304, no straddle
    const int sbase = i0 - bidx * SS + w * 16 + (l >> 4) * 4;
    #pragma unroll
    for (int nt = 0; nt < 4; ++nt) {
        const int col = j0 + nt * 16 + ar;
        const float bb = bias[col];
        #pragma unroll
        for (int r = 0; r < 4; ++r) {
            const float val = acc[nt][r] + bb;
            if (mode == 0) {
                outf[(size_t)(i0 + w * 16 + (l >> 4) * 4 + r) * FF + col] = val;
            } else {
                const size_t o = (((size_t)bidx * NH + (j0 >> 6)) * SS + sbase + r) * DD + nt * 16 + ar;
                if (mode == 2) {
                    outf[o] = val;
                } else {
                    ushort hv = f2bf_rne(val);
                    outhi[o] = hv;
                    outlo[o] = f2bf_rne(val - bfval(hv));
                }
            }
        }
    }
}

// ---------------------------------------------------------------------------
// Attention (recompute-flash): block = (16 q-rows, head, batch), 512 thr.
// Wave w owns contiguous cols [288w, 288w+288).
// Pass 1: QK^T (split MFMA) -> online (max,sum) in registers; cross-lane +
//         cross-wave merge via 1KB LDS.
// Pass 2: recompute QK^T, normalize, write attn weights, pack p->bf16 hi/lo
//         into per-wave LDS chunk, PV via MFMA. No barriers in main loops.
// ---------------------------------------------------------------------------
__global__ __launch_bounds__(512, 4) void attn_kernel(
    const ushort* __restrict__ qhi, const ushort* __restrict__ qlo,
    const ushort* __restrict__ khi, const ushort* __restrict__ klo,
    const ushort* __restrict__ vthi, const ushort* __restrict__ vtlo,
    float* __restrict__ attn_out, float* __restrict__ ctx)
{
    __shared__ __align__(16) ushort phi[8][16][40];   // 10,240 B
    __shared__ __align__(16) ushort plo[8][16][40];   // 10,240 B
    __shared__ float redm[8][16];                     //    512 B
    __shared__ float reds[8][16];                     //    512 B
    __shared__ __align__(16) float cred[8][16][68];   // 34,816 B

    const int t  = threadIdx.x, w = t >> 6, l = t & 63;
    const int ar = l & 15, kg = (l >> 4) * 8;
    const int qt = blockIdx.x, h = blockIdx.y, b = blockIdx.z;
    const int s0 = qt * QR;
    const int bh = b * NH + h;
    const size_t base = (size_t)bh * SS * DD;
    const float SC = 0.125f * 1.44269504f;   // log2(e)/sqrt(64)

    // q fragments (persist across both passes)
    const size_t qo = base + (size_t)(s0 + ar) * DD + kg;
    const bf16x8 qh0 = *(const bf16x8*)(qhi + qo);
    const bf16x8 qh1 = *(const bf16x8*)(qhi + qo + 32);
    const bf16x8 ql0 = *(const bf16x8*)(qlo + qo);
    const bf16x8 ql1 = *(const bf16x8*)(qlo + qo + 32);

    // ---- Pass 1: online max/sum ----
    float mrun[4], srun[4];
    #pragma unroll
    for (int r = 0; r < 4; ++r) { mrun[r] = -1e30f; srun[r] = 0.f; }

    for (int i = 0; i < 9; ++i) {
        const int ct0 = w * 18 + 2 * i;
        const size_t ko0 = base + (size_t)(ct0 * 16 + ar) * DD + kg;
        const size_t ko1 = ko0 + (size_t)16 * DD;
        bf16x8 kh00 = *(const bf16x8*)(khi + ko0);
        bf16x8 kh01 = *(const bf16x8*)(khi + ko0 + 32);
        bf16x8 kl00 = *(const bf16x8*)(klo + ko0);
        bf16x8 kl01 = *(const bf16x8*)(klo + ko0 + 32);
        bf16x8 kh10 = *(const bf16x8*)(khi + ko1);
        bf16x8 kh11 = *(const bf16x8*)(khi + ko1 + 32);
        bf16x8 kl10 = *(const bf16x8*)(klo + ko1);
        bf16x8 kl11 = *(const bf16x8*)(klo + ko1 + 32);
        f32x4 a0 = {0.f,0.f,0.f,0.f}, a1 = {0.f,0.f,0.f,0.f};
        __builtin_amdgcn_s_setprio(1);
        a0 = MFMA16(qh0, kh00, a0); a1 = MFMA16(qh0, kh10, a1);
        a0 = MFMA16(qh1, kh01, a0); a1 = MFMA16(qh1, kh11, a1);
        a0 = MFMA16(qh0, kl00, a0); a1 = MFMA16(qh0, kl10, a1);
        a0 = MFMA16(qh1, kl01, a0); a1 = MFMA16(qh1, kl11, a1);
        a0 = MFMA16(ql0, kh00, a0); a1 = MFMA16(ql0, kh10, a1);
        a0 = MFMA16(ql1, kh01, a0); a1 = MFMA16(ql1, kh11, a1);
        __builtin_amdgcn_s_setprio(0);
        #pragma unroll
        for (int r = 0; r < 4; ++r) {
            float v0 = a0[r] * SC, v1 = a1[r] * SC;
            float mn = fmaxf(mrun[r], fmaxf(v0, v1));
            srun[r] = srun[r] * exp2f(mrun[r] - mn) + exp2f(v0 - mn) + exp2f(v1 - mn);
            mrun[r] = mn;
        }
    }
    // cross-lane merge within 16-lane row groups
    #pragma unroll
    for (int off = 1; off <= 8; off <<= 1) {
        #pragma unroll
        for (int r = 0; r < 4; ++r) {
            float mo = __shfl_xor(mrun[r], off);
            float so = __shfl_xor(srun[r], off);
            float mn = fmaxf(mrun[r], mo);
            srun[r] = srun[r] * exp2f(mrun[r] - mn) + so * exp2f(mo - mn);
            mrun[r] = mn;
        }
    }
    if (ar == 0) {
        #pragma unroll
        for (int r = 0; r < 4; ++r) {
            redm[w][(l >> 4) * 4 + r] = mrun[r];
            reds[w][(l >> 4) * 4 + r] = srun[r];
        }
    }
    __syncthreads();
    float mf[4], inv[4];
    #pragma unroll
    for (int r = 0; r < 4; ++r) {
        const int rw = (l >> 4) * 4 + r;
        float mm = -1e30f, ssum = 0.f;
        #pragma unroll
        for (int w2 = 0; w2 < 8; ++w2) {
            float mw = redm[w2][rw], sw = reds[w2][rw];
            float mn = fmaxf(mm, mw);
            ssum = ssum * exp2f(mm - mn) + sw * exp2f(mw - mn);
            mm = mn;
        }
        mf[r] = mm;
        inv[r] = 1.0f / ssum;
    }

    // ---- Pass 2: recompute, normalize, emit attn, PV ----
    f32x4 acc[4];
    #pragma unroll
    for (int dt = 0; dt < 4; ++dt) acc[dt] = (f32x4){0.f, 0.f, 0.f, 0.f};
    float* aout = attn_out + ((size_t)bh * SS + s0) * SS;

    for (int i = 0; i < 9; ++i) {
        const int ct0 = w * 18 + 2 * i;
        const int c0  = ct0 * 16;
        const size_t ko0 = base + (size_t)(ct0 * 16 + ar) * DD + kg;
        const size_t ko1 = ko0 + (size_t)16 * DD;
        bf16x8 kh00 = *(const bf16x8*)(khi + ko0);
        bf16x8 kh01 = *(const bf16x8*)(khi + ko0 + 32);
        bf16x8 kl00 = *(const bf16x8*)(klo + ko0);
        bf16x8 kl01 = *(const bf16x8*)(klo + ko0 + 32);
        bf16x8 kh10 = *(const bf16x8*)(khi + ko1);
        bf16x8 kh11 = *(const bf16x8*)(khi + ko1 + 32);
        bf16x8 kl10 = *(const bf16x8*)(klo + ko1);
        bf16x8 kl11 = *(const bf16x8*)(klo + ko1 + 32);
        f32x4 a0 = {0.f,0.f,0.f,0.f}, a1 = {0.f,0.f,0.f,0.f};
        __builtin_amdgcn_s_setprio(1);
        a0 = MFMA16(qh0, kh00, a0); a1 = MFMA16(qh0, kh10, a1);
        a0 = MFMA16(qh1, kh01, a0); a1 = MFMA16(qh1, kh11, a1);
        a0 = MFMA16(qh0, kl00, a0); a1 = MFMA16(qh0, kl10, a1);
        a0 = MFMA16(qh1, kl01, a0); a1 = MFMA16(qh1, kl11, a1);
        a0 = MFMA16(ql0, kh00, a0); a1 = MFMA16(ql0, kh10, a1);
        a0 = MFMA16(ql1, kh01, a0); a1 = MFMA16(ql1, kh11, a1);
        __builtin_amdgcn_s_setprio(0);
        #pragma unroll
        for (int r = 0; r < 4; ++r) {
            const int rw = (l >> 4) * 4 + r;
            float p0 = exp2f(a0[r] * SC - mf[r]) * inv[r];
            float p1 = exp2f(a1[r] * SC - mf[r]) * inv[r];
            aout[(size_t)rw * SS + c0 + ar]      = p0;
            aout[(size_t)rw * SS + c0 + 16 + ar] = p1;
            ushort h0 = f2bf_rne(p0);
            ushort h1 = f2bf_rne(p1);
            phi[w][rw][ar]      = h0;
            phi[w][rw][16 + ar] = h1;
            plo[w][rw][ar]      = f2bf_rne(p0 - bfval(h0));
            plo[w][rw][16 + ar] = f2bf_rne(p1 - bfval(h1));
        }
        bf16x8 pah = *(const bf16x8*)&phi[w][ar][kg];
        bf16x8 pal = *(const bf16x8*)&plo[w][ar][kg];
        __builtin_amdgcn_s_setprio(1);
        #pragma unroll
        for (int dt = 0; dt < 4; ++dt) {
            const size_t vo = ((size_t)bh * DD + dt * 16 + ar) * SS + c0 + kg;
            bf16x8 vh = *(const bf16x8*)(vthi + vo);
            bf16x8 vl = *(const bf16x8*)(vtlo + vo);
            acc[dt] = MFMA16(pah, vh, acc[dt]);
            acc[dt] = MFMA16(pah, vl, acc[dt]);
            acc[dt] = MFMA16(pal, vh, acc[dt]);
        }
        __builtin_amdgcn_s_setprio(0);
    }

    // ---- cross-wave ctx reduction ----
    #pragma unroll
    for (int dt = 0; dt < 4; ++dt) {
        #pragma unroll
        for (int r = 0; r < 4; ++r)
            cred[w][(l >> 4) * 4 + r][dt * 16 + ar] = acc[dt][r];
    }
    __syncthreads();
    #pragma unroll
    for (int idx = t; idx < 1024; idx += 512) {
        const int rw = idx >> 6, d = idx & 63;
        float sum = 0.f;
        #pragma unroll
        for (int w2 = 0; w2 < 8; ++w2) sum += cred[w2][rw][d];
        ctx[((size_t)b * SS + s0 + rw) * FF + h * DD + d] = sum;
    }
}

extern "C" void kernel_launch(void* const* d_in, const int* in_sizes, int n_in,
                              void* d_out, int out_size, void* d_ws, size_t ws_size,
                              hipStream_t stream) {
    (void)in_sizes; (void)n_in; (void)out_size; (void)ws_size;
    const float* query = (const float*)d_in[0];
    const float* value = (const float*)d_in[1];
    const float* keys  = (const float*)d_in[2];
    const float* wq_w  = (const float*)d_in[3];
    const float* wq_b  = (const float*)d_in[4];
    const float* wk_w  = (const float*)d_in[5];
    const float* wk_b  = (const float*)d_in[6];
    const float* wv_w  = (const float*)d_in[7];
    const float* wv_b  = (const float*)d_in[8];
    const float* wo_w  = (const float*)d_in[9];
    const float* wo_b  = (const float*)d_in[10];

    float* out  = (float*)d_out;
    float* attn = out + (size_t)BB * SS * FF;

    const size_t NQ = (size_t)BB * NH * SS * DD;   // 4,718,592
    ushort* qhi    = (ushort*)d_ws;
    ushort* qlo    = qhi + NQ;
    ushort* khi    = qlo + NQ;
    ushort* klo    = khi + NQ;
    ushort* vthi   = klo + NQ;
    ushort* vtlo   = vthi + NQ;
    float*  vstage = (float*)(vtlo + NQ);          // NQ floats; doubles as ctx
    ushort* wthi   = (ushort*)(vstage + NQ);       // 262,144
    ushort* wtlo   = wthi + (size_t)FF * FF;

    dim3 gwt(FF / 64, FF / 64);
    dim3 gproj(BSR / 64, FF / 64);
    dim3 gvt(SS / 64, BB * NH);
    dim3 gattn(SS / QR, NH, BB);

    wtsplit_kernel<<<gwt, 256, 0, stream>>>(wq_w, wthi, wtlo);
    proj_mfma<<<gproj, 256, 0, stream>>>(query, wthi, wtlo, wq_b, nullptr, qhi, qlo, 1);
    wtsplit_kernel<<<gwt, 256, 0, stream>>>(wk_w, wthi, wtlo);
    proj_mfma<<<gproj, 256, 0, stream>>>(keys, wthi, wtlo, wk_b, nullptr, khi, klo, 1);
    wtsplit_kernel<<<gwt, 256, 0, stream>>>(wv_w, wthi, wtlo);
    proj_mfma<<<gproj, 256, 0, stream>>>(value, wthi, wtlo, wv_b, vstage, nullptr, nullptr, 2);
    vtsplit_kernel<<<gvt, 256, 0, stream>>>(vstage, vthi, vtlo);

    attn_kernel<<<gattn, 512, 0, stream>>>(qhi, qlo, khi, klo, vthi, vtlo, attn, vstage);

    wtsplit_kernel<<<gwt, 256, 0, stream>>>(wo_w, wthi, wtlo);
    proj_mfma<<<gproj, 256, 0, stream>>>(vstage, wthi, wtlo, wo_b, out, nullptr, nullptr, 0);
}

// Round 4
// 1135.558 us; speedup vs baseline: 1.1402x; 1.1402x over previous
//
#include <hip/hip_runtime.h>
#include <cstddef>

#define BB 4
#define SS 2304      // 48*48
#define FF 512
#define NH 8
#define DD 64
#define BSR (BB*SS)  // 9216 rows

typedef __attribute__((ext_vector_type(8))) short bf16x8;
typedef __attribute__((ext_vector_type(4))) float f32x4;
#define MFMA16(a,b,c) __builtin_amdgcn_mfma_f32_16x16x32_bf16((a),(b),(c),0,0,0)

__device__ __forceinline__ ushort f2bf_rne(float x) {
    uint u = __float_as_uint(x);
    uint r = u + 0x7fffu + ((u >> 16) & 1u);
    return (ushort)(r >> 16);
}
__device__ __forceinline__ float bfval(ushort h) {
    return __uint_as_float((uint)h << 16);
}

// ---------------------------------------------------------------------------
// Weight transpose+split: W[k][n] (512x512 f32) -> Wt{hi,lo}[n][k] bf16
// ---------------------------------------------------------------------------
__global__ __launch_bounds__(256) void wtsplit_kernel(
    const float* __restrict__ w, ushort* __restrict__ whi, ushort* __restrict__ wlo)
{
    __shared__ __align__(16) float tile[64][68];
    const int t  = threadIdx.x;
    const int kt = blockIdx.x;
    const int nt = blockIdx.y;
    {
        const int r  = t >> 2;
        const int cg = (t & 3) * 16;
        const float* src = w + (size_t)(kt * 64 + r) * FF + nt * 64 + cg;
        #pragma unroll
        for (int j = 0; j < 4; ++j)
            *(float4*)&tile[r][cg + 4 * j] = *(const float4*)(src + 4 * j);
    }
    __syncthreads();
    {
        const int n  = t >> 2;
        const int kg = (t & 3) * 16;
        union { ushort s[16]; uint4 q[2]; } H, L;
        #pragma unroll
        for (int j = 0; j < 16; ++j) {
            float x = tile[kg + j][n];
            ushort hh = f2bf_rne(x);
            H.s[j] = hh;
            L.s[j] = f2bf_rne(x - bfval(hh));
        }
        size_t off = (size_t)(nt * 64 + n) * FF + kt * 64 + kg;
        *(uint4*)(whi + off)     = H.q[0];
        *(uint4*)(whi + off + 8) = H.q[1];
        *(uint4*)(wlo + off)     = L.q[0];
        *(uint4*)(wlo + off + 8) = L.q[1];
    }
}

// ---------------------------------------------------------------------------
// V transpose+split: v[bh][s][d] f32 -> vt{hi,lo}[bh][d][s] bf16
// ---------------------------------------------------------------------------
__global__ __launch_bounds__(256) void vtsplit_kernel(
    const float* __restrict__ v, ushort* __restrict__ vthi, ushort* __restrict__ vtlo)
{
    __shared__ __align__(16) float tile[64][68];
    const int t  = threadIdx.x;
    const int st = blockIdx.x;
    const int bh = blockIdx.y;
    {
        const int r  = t >> 2;
        const int cg = (t & 3) * 16;
        const float* src = v + ((size_t)bh * SS + st * 64 + r) * DD + cg;
        #pragma unroll
        for (int j = 0; j < 4; ++j)
            *(float4*)&tile[r][cg + 4 * j] = *(const float4*)(src + 4 * j);
    }
    __syncthreads();
    {
        const int d  = t >> 2;
        const int sg = (t & 3) * 16;
        union { ushort s[16]; uint4 q[2]; } H, L;
        #pragma unroll
        for (int j = 0; j < 16; ++j) {
            float x = tile[sg + j][d];
            ushort hh = f2bf_rne(x);
            H.s[j] = hh;
            L.s[j] = f2bf_rne(x - bfval(hh));
        }
        size_t off = ((size_t)bh * DD + d) * SS + st * 64 + sg;
        *(uint4*)(vthi + off)     = H.q[0];
        *(uint4*)(vthi + off + 8) = H.q[1];
        *(uint4*)(vtlo + off)     = L.q[0];
        *(uint4*)(vtlo + off + 8) = L.q[1];
    }
}

// ---------------------------------------------------------------------------
// Projection GEMM via split-bf16 MFMA: out = X @ W + b.  Tile 64x128.
// X fp32 (converted hi/lo in-register); Wt pre-split [n][k].
// mode 0: fp32 out[row][512]; mode 1: ushort hi/lo head-split; mode 2: f32 hs
// ---------------------------------------------------------------------------
__global__ __launch_bounds__(256) void proj_mfma(
    const float* __restrict__ X, const ushort* __restrict__ wth,
    const ushort* __restrict__ wtl, const float* __restrict__ bias,
    float* __restrict__ outf, ushort* __restrict__ outhi,
    ushort* __restrict__ outlo, int mode)
{
    const int t  = threadIdx.x, w = t >> 6, l = t & 63;
    const int ar = l & 15, kg = (l >> 4) * 8;
    const int i0 = blockIdx.x * 64, j0 = blockIdx.y * 128;
    const int arow = i0 + w * 16 + ar;

    f32x4 acc[8];
    #pragma unroll
    for (int nt = 0; nt < 8; ++nt) acc[nt] = (f32x4){0.f, 0.f, 0.f, 0.f};

    for (int kk = 0; kk < FF; kk += 32) {
        const float* xr = X + (size_t)arow * FF + kk + kg;
        float4 f0 = *(const float4*)xr;
        float4 f1 = *(const float4*)(xr + 4);
        ushort h0 = f2bf_rne(f0.x), h1 = f2bf_rne(f0.y), h2 = f2bf_rne(f0.z), h3 = f2bf_rne(f0.w);
        ushort h4 = f2bf_rne(f1.x), h5 = f2bf_rne(f1.y), h6 = f2bf_rne(f1.z), h7 = f2bf_rne(f1.w);
        union { uint u[4]; bf16x8 v; } ah, al;
        ah.u[0] = (uint)h0 | ((uint)h1 << 16);
        ah.u[1] = (uint)h2 | ((uint)h3 << 16);
        ah.u[2] = (uint)h4 | ((uint)h5 << 16);
        ah.u[3] = (uint)h6 | ((uint)h7 << 16);
        al.u[0] = (uint)f2bf_rne(f0.x - bfval(h0)) | ((uint)f2bf_rne(f0.y - bfval(h1)) << 16);
        al.u[1] = (uint)f2bf_rne(f0.z - bfval(h2)) | ((uint)f2bf_rne(f0.w - bfval(h3)) << 16);
        al.u[2] = (uint)f2bf_rne(f1.x - bfval(h4)) | ((uint)f2bf_rne(f1.y - bfval(h5)) << 16);
        al.u[3] = (uint)f2bf_rne(f1.z - bfval(h6)) | ((uint)f2bf_rne(f1.w - bfval(h7)) << 16);
        #pragma unroll
        for (int nt = 0; nt < 8; ++nt) {
            const size_t wo = (size_t)(j0 + nt * 16 + ar) * FF + kk + kg;
            bf16x8 bh = *(const bf16x8*)(wth + wo);
            bf16x8 bl = *(const bf16x8*)(wtl + wo);
            acc[nt] = MFMA16(ah.v, bh, acc[nt]);
            acc[nt] = MFMA16(ah.v, bl, acc[nt]);
            acc[nt] = MFMA16(al.v, bh, acc[nt]);
        }
    }

    const int bidx = i0 / SS;
    #pragma unroll
    for (int nt = 0; nt < 8; ++nt) {
        const int col = j0 + nt * 16 + ar;
        const float bb = bias[col];
        #pragma unroll
        for (int r = 0; r < 4; ++r) {
            const int rowl = w * 16 + (l >> 4) * 4 + r;
            const float val = acc[nt][r] + bb;
            if (mode == 0) {
                outf[(size_t)(i0 + rowl) * FF + col] = val;
            } else {
                const int s = (i0 - bidx * SS) + rowl;
                const size_t o = (((size_t)bidx * NH + (col >> 6)) * SS + s) * DD + (col & 63);
                if (mode == 2) {
                    outf[o] = val;
                } else {
                    ushort hv = f2bf_rne(val);
                    outhi[o] = hv;
                    outlo[o] = f2bf_rne(val - bfval(hv));
                }
            }
        }
    }
}

// ---------------------------------------------------------------------------
// Stats: per (q-tile 64, bh). 512 thr = 8 waves (qs=w&3 x kh=w>>2).
// K-hi staged in LDS (swizzled, dbuf, 1 barrier/tile). 2-term QK^T.
// Online (m,s) per row -> stats[bh][row] = (m, 1/s), log2 units.
// ---------------------------------------------------------------------------
__global__ __launch_bounds__(512) void stats_kernel(
    const ushort* __restrict__ qhi, const ushort* __restrict__ qlo,
    const ushort* __restrict__ khi, float2* __restrict__ stats)
{
    __shared__ ushort KS[2][4096];
    __shared__ float redM[2][64];
    __shared__ float redS[2][64];

    const int t = threadIdx.x, w = t >> 6, l = t & 63;
    const int ar = l & 15, kgi = l >> 4, kg = kgi * 8;
    const int qs = w & 3, kh = w >> 2;
    const int qt = blockIdx.x, bh = blockIdx.y;
    const int q0 = qt * 64;
    const size_t base = (size_t)bh * SS * DD;
    const float SC = 0.125f * 1.44269504f;

    const size_t qo = base + (size_t)(q0 + qs * 16 + ar) * DD + kg;
    const bf16x8 qh0 = *(const bf16x8*)(qhi + qo);
    const bf16x8 qh1 = *(const bf16x8*)(qhi + qo + 32);
    const bf16x8 ql0 = *(const bf16x8*)(qlo + qo);
    const bf16x8 ql1 = *(const bf16x8*)(qlo + qo + 32);

    const int srow = t >> 3, sc8 = t & 7;
    const int sidx = srow * 64 + ((sc8 ^ (srow & 7)) << 3);
    const ushort* ksrc = khi + base + srow * 64 + sc8 * 8;

    uint4 rg = *(const uint4*)ksrc;
    *(uint4*)&KS[0][sidx] = rg;
    __syncthreads();

    const int sw  = ar & 7;
    const int i00 = kh * 2048 + ar * 64;
    const int i01 = i00 + 1024;
    const int s00 = (kgi ^ sw) << 3;
    const int s01 = ((4 | kgi) ^ sw) << 3;

    float m[4], s[4];
    #pragma unroll
    for (int r = 0; r < 4; ++r) { m[r] = -1e30f; s[r] = 0.f; }

    for (int kt = 0; kt < 36; ++kt) {
        const ushort* KC = &KS[kt & 1][0];
        if (kt < 35) rg = *(const uint4*)(ksrc + (size_t)(kt + 1) * 4096);
        bf16x8 b00 = *(const bf16x8*)&KC[i00 + s00];
        bf16x8 b01 = *(const bf16x8*)&KC[i00 + s01];
        bf16x8 b10 = *(const bf16x8*)&KC[i01 + s00];
        bf16x8 b11 = *(const bf16x8*)&KC[i01 + s01];
        f32x4 a0 = {0.f,0.f,0.f,0.f}, a1 = {0.f,0.f,0.f,0.f};
        a0 = MFMA16(qh0, b00, a0); a1 = MFMA16(qh0, b10, a1);
        a0 = MFMA16(qh1, b01, a0); a1 = MFMA16(qh1, b11, a1);
        a0 = MFMA16(ql0, b00, a0); a1 = MFMA16(ql0, b10, a1);
        a0 = MFMA16(ql1, b01, a0); a1 = MFMA16(ql1, b11, a1);
        #pragma unroll
        for (int r = 0; r < 4; ++r) {
            float v0 = a0[r] * SC, v1 = a1[r] * SC;
            float nm = fmaxf(m[r], fmaxf(v0, v1));
            s[r] = s[r] * exp2f(m[r] - nm) + exp2f(v0 - nm) + exp2f(v1 - nm);
            m[r] = nm;
        }
        if (kt < 35) *(uint4*)&KS[(kt & 1) ^ 1][sidx] = rg;
        __syncthreads();
    }

    #pragma unroll
    for (int off = 1; off <= 8; off <<= 1) {
        #pragma unroll
        for (int r = 0; r < 4; ++r) {
            float mo = __shfl_xor(m[r], off);
            float so = __shfl_xor(s[r], off);
            float nm = fmaxf(m[r], mo);
            s[r] = s[r] * exp2f(m[r] - nm) + so * exp2f(mo - nm);
            m[r] = nm;
        }
    }
    if (ar == 0) {
        #pragma unroll
        for (int r = 0; r < 4; ++r) {
            redM[kh][qs * 16 + kgi * 4 + r] = m[r];
            redS[kh][qs * 16 + kgi * 4 + r] = s[r];
        }
    }
    __syncthreads();
    if (t < 64) {
        float m0 = redM[0][t], m1 = redM[1][t];
        float s0 = redS[0][t], s1 = redS[1][t];
        float M  = fmaxf(m0, m1);
        float Sv = s0 * exp2f(m0 - M) + s1 * exp2f(m1 - M);
        stats[(size_t)bh * SS + q0 + t] = make_float2(M, 1.0f / Sv);
    }
}

// ---------------------------------------------------------------------------
// Emit: recompute QK^T (3-term, K hi+lo staged), normalize with stats,
// write attn fp32 (coalesced 64B segments). Pure streaming, 1 barrier/tile.
// ---------------------------------------------------------------------------
__global__ __launch_bounds__(512) void emit_kernel(
    const ushort* __restrict__ qhi, const ushort* __restrict__ qlo,
    const ushort* __restrict__ khi, const ushort* __restrict__ klo,
    const float2* __restrict__ stats, float* __restrict__ attn_out)
{
    __shared__ ushort KH[2][4096];
    __shared__ ushort KL[2][4096];

    const int t = threadIdx.x, w = t >> 6, l = t & 63;
    const int ar = l & 15, kgi = l >> 4, kg = kgi * 8;
    const int qs = w & 3, kh = w >> 2;
    const int qt = blockIdx.x, bh = blockIdx.y;
    const int q0 = qt * 64;
    const size_t base = (size_t)bh * SS * DD;
    const float SC = 0.125f * 1.44269504f;

    const size_t qo = base + (size_t)(q0 + qs * 16 + ar) * DD + kg;
    const bf16x8 qh0 = *(const bf16x8*)(qhi + qo);
    const bf16x8 qh1 = *(const bf16x8*)(qhi + qo + 32);
    const bf16x8 ql0 = *(const bf16x8*)(qlo + qo);
    const bf16x8 ql1 = *(const bf16x8*)(qlo + qo + 32);

    float m[4], inv[4];
    #pragma unroll
    for (int r = 0; r < 4; ++r) {
        float2 st = stats[(size_t)bh * SS + q0 + qs * 16 + kgi * 4 + r];
        m[r] = st.x; inv[r] = st.y;
    }

    const int srow = t >> 3, sc8 = t & 7;
    const int sidx = srow * 64 + ((sc8 ^ (srow & 7)) << 3);
    const ushort* khsrc = khi + base + srow * 64 + sc8 * 8;
    const ushort* klsrc = klo + base + srow * 64 + sc8 * 8;

    uint4 rgh = *(const uint4*)khsrc;
    uint4 rgl = *(const uint4*)klsrc;
    *(uint4*)&KH[0][sidx] = rgh;
    *(uint4*)&KL[0][sidx] = rgl;
    __syncthreads();

    const int sw  = ar & 7;
    const int i00 = kh * 2048 + ar * 64;
    const int i01 = i00 + 1024;
    const int s00 = (kgi ^ sw) << 3;
    const int s01 = ((4 | kgi) ^ sw) << 3;

    float* abase = attn_out + ((size_t)bh * SS + q0 + qs * 16) * SS + kh * 32;

    for (int kt = 0; kt < 36; ++kt) {
        const ushort* KHc = &KH[kt & 1][0];
        const ushort* KLc = &KL[kt & 1][0];
        if (kt < 35) {
            rgh = *(const uint4*)(khsrc + (size_t)(kt + 1) * 4096);
            rgl = *(const uint4*)(klsrc + (size_t)(kt + 1) * 4096);
        }
        bf16x8 bh00 = *(const bf16x8*)&KHc[i00 + s00];
        bf16x8 bh01 = *(const bf16x8*)&KHc[i00 + s01];
        bf16x8 bl00 = *(const bf16x8*)&KLc[i00 + s00];
        bf16x8 bl01 = *(const bf16x8*)&KLc[i00 + s01];
        bf16x8 bh10 = *(const bf16x8*)&KHc[i01 + s00];
        bf16x8 bh11 = *(const bf16x8*)&KHc[i01 + s01];
        bf16x8 bl10 = *(const bf16x8*)&KLc[i01 + s00];
        bf16x8 bl11 = *(const bf16x8*)&KLc[i01 + s01];
        f32x4 a0 = {0.f,0.f,0.f,0.f}, a1 = {0.f,0.f,0.f,0.f};
        a0 = MFMA16(qh0, bh00, a0); a1 = MFMA16(qh0, bh10, a1);
        a0 = MFMA16(qh0, bl00, a0); a1 = MFMA16(qh0, bl10, a1);
        a0 = MFMA16(ql0, bh00, a0); a1 = MFMA16(ql0, bh10, a1);
        a0 = MFMA16(qh1, bh01, a0); a1 = MFMA16(qh1, bh11, a1);
        a0 = MFMA16(qh1, bl01, a0); a1 = MFMA16(qh1, bl11, a1);
        a0 = MFMA16(ql1, bh01, a0); a1 = MFMA16(ql1, bh11, a1);

        float* arow = abase + (size_t)kt * 64;
        #pragma unroll
        for (int r = 0; r < 4; ++r) {
            const size_t ro = (size_t)(kgi * 4 + r) * SS;
            float p0 = exp2f(a0[r] * SC - m[r]) * inv[r];
            float p1 = exp2f(a1[r] * SC - m[r]) * inv[r];
            arow[ro + ar]      = p0;
            arow[ro + 16 + ar] = p1;
        }
        if (kt < 35) {
            *(uint4*)&KH[(kt & 1) ^ 1][sidx] = rgh;
            *(uint4*)&KL[(kt & 1) ^ 1][sidx] = rgl;
        }
        __syncthreads();
    }
}

// ---------------------------------------------------------------------------
// PV GEMM: ctx[b][s][h*64+d] = attn(fp32->bf16 hi) @ vt{hi,lo}.
// Per (q-tile 64, bh) block, 256 thr = 4 waves x 16 rows. K=2304.
// ---------------------------------------------------------------------------
__global__ __launch_bounds__(256) void pv_kernel(
    const float* __restrict__ attn, const ushort* __restrict__ vthi,
    const ushort* __restrict__ vtlo, float* __restrict__ ctx)
{
    const int t = threadIdx.x, w = t >> 6, l = t & 63;
    const int ar = l & 15, kg = (l >> 4) * 8;
    const int qt = blockIdx.x, bh = blockIdx.y;
    const int q0 = qt * 64, b = bh >> 3, h = bh & 7;

    const float* ap = attn + ((size_t)bh * SS + q0 + w * 16 + ar) * SS + kg;
    const ushort* vhb = vthi + (size_t)bh * DD * SS;
    const ushort* vlb = vtlo + (size_t)bh * DD * SS;

    f32x4 acc[4];
    #pragma unroll
    for (int nt = 0; nt < 4; ++nt) acc[nt] = (f32x4){0.f, 0.f, 0.f, 0.f};

    for (int kk = 0; kk < SS; kk += 32) {
        float4 x0 = *(const float4*)(ap + kk);
        float4 x1 = *(const float4*)(ap + kk + 4);
        union { uint u[4]; bf16x8 v; } ah;
        ah.u[0] = (uint)f2bf_rne(x0.x) | ((uint)f2bf_rne(x0.y) << 16);
        ah.u[1] = (uint)f2bf_rne(x0.z) | ((uint)f2bf_rne(x0.w) << 16);
        ah.u[2] = (uint)f2bf_rne(x1.x) | ((uint)f2bf_rne(x1.y) << 16);
        ah.u[3] = (uint)f2bf_rne(x1.z) | ((uint)f2bf_rne(x1.w) << 16);
        #pragma unroll
        for (int nt = 0; nt < 4; ++nt) {
            const size_t vo = (size_t)(nt * 16 + ar) * SS + kk + kg;
            bf16x8 vh = *(const bf16x8*)(vhb + vo);
            bf16x8 vl = *(const bf16x8*)(vlb + vo);
            acc[nt] = MFMA16(ah.v, vh, acc[nt]);
            acc[nt] = MFMA16(ah.v, vl, acc[nt]);
        }
    }

    #pragma unroll
    for (int nt = 0; nt < 4; ++nt) {
        #pragma unroll
        for (int r = 0; r < 4; ++r) {
            const int row = q0 + w * 16 + (l >> 4) * 4 + r;
            ctx[((size_t)b * SS + row) * FF + h * DD + nt * 16 + ar] = acc[nt][r];
        }
    }
}

extern "C" void kernel_launch(void* const* d_in, const int* in_sizes, int n_in,
                              void* d_out, int out_size, void* d_ws, size_t ws_size,
                              hipStream_t stream) {
    (void)in_sizes; (void)n_in; (void)out_size; (void)ws_size;
    const float* query = (const float*)d_in[0];
    const float* value = (const float*)d_in[1];
    const float* keys  = (const float*)d_in[2];
    const float* wq_w  = (const float*)d_in[3];
    const float* wq_b  = (const float*)d_in[4];
    const float* wk_w  = (const float*)d_in[5];
    const float* wk_b  = (const float*)d_in[6];
    const float* wv_w  = (const float*)d_in[7];
    const float* wv_b  = (const float*)d_in[8];
    const float* wo_w  = (const float*)d_in[9];
    const float* wo_b  = (const float*)d_in[10];

    float* out  = (float*)d_out;
    float* attn = out + (size_t)BB * SS * FF;

    const size_t NQ = (size_t)BB * NH * SS * DD;   // 4,718,592
    ushort* qhi    = (ushort*)d_ws;
    ushort* qlo    = qhi + NQ;
    ushort* khi    = qlo + NQ;
    ushort* klo    = khi + NQ;
    ushort* vthi   = klo + NQ;
    ushort* vtlo   = vthi + NQ;
    float*  vstage = (float*)(vtlo + NQ);          // NQ f32; later ctx
    ushort* wthi   = (ushort*)(vstage + NQ);
    ushort* wtlo   = wthi + (size_t)FF * FF;
    float2* stats  = (float2*)(wtlo + (size_t)FF * FF);

    dim3 gwt(FF / 64, FF / 64);
    dim3 gproj(BSR / 64, FF / 128);
    dim3 gvt(SS / 64, BB * NH);
    dim3 gse(SS / 64, BB * NH);

    wtsplit_kernel<<<gwt, 256, 0, stream>>>(wq_w, wthi, wtlo);
    proj_mfma<<<gproj, 256, 0, stream>>>(query, wthi, wtlo, wq_b, nullptr, qhi, qlo, 1);
    wtsplit_kernel<<<gwt, 256, 0, stream>>>(wk_w, wthi, wtlo);
    proj_mfma<<<gproj, 256, 0, stream>>>(keys, wthi, wtlo, wk_b, nullptr, khi, klo, 1);
    wtsplit_kernel<<<gwt, 256, 0, stream>>>(wv_w, wthi, wtlo);
    proj_mfma<<<gproj, 256, 0, stream>>>(value, wthi, wtlo, wv_b, vstage, nullptr, nullptr, 2);
    vtsplit_kernel<<<gvt, 256, 0, stream>>>(vstage, vthi, vtlo);

    stats_kernel<<<gse, 512, 0, stream>>>(qhi, qlo, khi, stats);
    emit_kernel<<<gse, 512, 0, stream>>>(qhi, qlo, khi, klo, stats, attn);
    pv_kernel<<<gse, 256, 0, stream>>>(attn, vthi, vtlo, vstage);

    wtsplit_kernel<<<gwt, 256, 0, stream>>>(wo_w, wthi, wtlo);
    proj_mfma<<<gproj, 256, 0, stream>>>(vstage, wthi, wtlo, wo_b, out, nullptr, nullptr, 0);
}

// Round 5
// 851.947 us; speedup vs baseline: 1.5198x; 1.3329x over previous
//
#include <hip/hip_runtime.h>
#include <cstddef>

#define BB 4
#define SS 2304      // 48*48
#define FF 512
#define NH 8
#define DD 64
#define BSR (BB*SS)  // 9216 rows

typedef __attribute__((ext_vector_type(8))) short bf16x8;
typedef __attribute__((ext_vector_type(4))) float f32x4;
#define MFMA16(a,b,c) __builtin_amdgcn_mfma_f32_16x16x32_bf16((a),(b),(c),0,0,0)

__device__ __forceinline__ ushort f2bf_rne(float x) {
    uint u = __float_as_uint(x);
    uint r = u + 0x7fffu + ((u >> 16) & 1u);
    return (ushort)(r >> 16);
}
__device__ __forceinline__ float bfval(ushort h) {
    return __uint_as_float((uint)h << 16);
}

// ---------------------------------------------------------------------------
// Weight transpose+split: W[k][n] (512x512 f32) -> Wt{hi,lo}[n][k] bf16
// ---------------------------------------------------------------------------
__global__ __launch_bounds__(256) void wtsplit_kernel(
    const float* __restrict__ w, ushort* __restrict__ whi, ushort* __restrict__ wlo)
{
    __shared__ __align__(16) float tile[64][68];
    const int t  = threadIdx.x;
    const int kt = blockIdx.x;
    const int nt = blockIdx.y;
    {
        const int r  = t >> 2;
        const int cg = (t & 3) * 16;
        const float* src = w + (size_t)(kt * 64 + r) * FF + nt * 64 + cg;
        #pragma unroll
        for (int j = 0; j < 4; ++j)
            *(float4*)&tile[r][cg + 4 * j] = *(const float4*)(src + 4 * j);
    }
    __syncthreads();
    {
        const int n  = t >> 2;
        const int kg = (t & 3) * 16;
        union { ushort s[16]; uint4 q[2]; } H, L;
        #pragma unroll
        for (int j = 0; j < 16; ++j) {
            float x = tile[kg + j][n];
            ushort hh = f2bf_rne(x);
            H.s[j] = hh;
            L.s[j] = f2bf_rne(x - bfval(hh));
        }
        size_t off = (size_t)(nt * 64 + n) * FF + kt * 64 + kg;
        *(uint4*)(whi + off)     = H.q[0];
        *(uint4*)(whi + off + 8) = H.q[1];
        *(uint4*)(wlo + off)     = L.q[0];
        *(uint4*)(wlo + off + 8) = L.q[1];
    }
}

// ---------------------------------------------------------------------------
// V transpose+split: v[bh][s][d] f32 -> vt{hi,lo}[bh][d][s] bf16
// ---------------------------------------------------------------------------
__global__ __launch_bounds__(256) void vtsplit_kernel(
    const float* __restrict__ v, ushort* __restrict__ vthi, ushort* __restrict__ vtlo)
{
    __shared__ __align__(16) float tile[64][68];
    const int t  = threadIdx.x;
    const int st = blockIdx.x;
    const int bh = blockIdx.y;
    {
        const int r  = t >> 2;
        const int cg = (t & 3) * 16;
        const float* src = v + ((size_t)bh * SS + st * 64 + r) * DD + cg;
        #pragma unroll
        for (int j = 0; j < 4; ++j)
            *(float4*)&tile[r][cg + 4 * j] = *(const float4*)(src + 4 * j);
    }
    __syncthreads();
    {
        const int d  = t >> 2;
        const int sg = (t & 3) * 16;
        union { ushort s[16]; uint4 q[2]; } H, L;
        #pragma unroll
        for (int j = 0; j < 16; ++j) {
            float x = tile[sg + j][d];
            ushort hh = f2bf_rne(x);
            H.s[j] = hh;
            L.s[j] = f2bf_rne(x - bfval(hh));
        }
        size_t off = ((size_t)bh * DD + d) * SS + st * 64 + sg;
        *(uint4*)(vthi + off)     = H.q[0];
        *(uint4*)(vthi + off + 8) = H.q[1];
        *(uint4*)(vtlo + off)     = L.q[0];
        *(uint4*)(vtlo + off + 8) = L.q[1];
    }
}

// ---------------------------------------------------------------------------
// Projection GEMM via split-bf16 MFMA: out = X @ W + b.  Tile 64x128.
// ---------------------------------------------------------------------------
__global__ __launch_bounds__(256) void proj_mfma(
    const float* __restrict__ X, const ushort* __restrict__ wth,
    const ushort* __restrict__ wtl, const float* __restrict__ bias,
    float* __restrict__ outf, ushort* __restrict__ outhi,
    ushort* __restrict__ outlo, int mode)
{
    const int t  = threadIdx.x, w = t >> 6, l = t & 63;
    const int ar = l & 15, kg = (l >> 4) * 8;
    const int i0 = blockIdx.x * 64, j0 = blockIdx.y * 128;
    const int arow = i0 + w * 16 + ar;

    f32x4 acc[8];
    #pragma unroll
    for (int nt = 0; nt < 8; ++nt) acc[nt] = (f32x4){0.f, 0.f, 0.f, 0.f};

    for (int kk = 0; kk < FF; kk += 32) {
        const float* xr = X + (size_t)arow * FF + kk + kg;
        float4 f0 = *(const float4*)xr;
        float4 f1 = *(const float4*)(xr + 4);
        ushort h0 = f2bf_rne(f0.x), h1 = f2bf_rne(f0.y), h2 = f2bf_rne(f0.z), h3 = f2bf_rne(f0.w);
        ushort h4 = f2bf_rne(f1.x), h5 = f2bf_rne(f1.y), h6 = f2bf_rne(f1.z), h7 = f2bf_rne(f1.w);
        union { uint u[4]; bf16x8 v; } ah, al;
        ah.u[0] = (uint)h0 | ((uint)h1 << 16);
        ah.u[1] = (uint)h2 | ((uint)h3 << 16);
        ah.u[2] = (uint)h4 | ((uint)h5 << 16);
        ah.u[3] = (uint)h6 | ((uint)h7 << 16);
        al.u[0] = (uint)f2bf_rne(f0.x - bfval(h0)) | ((uint)f2bf_rne(f0.y - bfval(h1)) << 16);
        al.u[1] = (uint)f2bf_rne(f0.z - bfval(h2)) | ((uint)f2bf_rne(f0.w - bfval(h3)) << 16);
        al.u[2] = (uint)f2bf_rne(f1.x - bfval(h4)) | ((uint)f2bf_rne(f1.y - bfval(h5)) << 16);
        al.u[3] = (uint)f2bf_rne(f1.z - bfval(h6)) | ((uint)f2bf_rne(f1.w - bfval(h7)) << 16);
        #pragma unroll
        for (int nt = 0; nt < 8; ++nt) {
            const size_t wo = (size_t)(j0 + nt * 16 + ar) * FF + kk + kg;
            bf16x8 bh = *(const bf16x8*)(wth + wo);
            bf16x8 bl = *(const bf16x8*)(wtl + wo);
            acc[nt] = MFMA16(ah.v, bh, acc[nt]);
            acc[nt] = MFMA16(ah.v, bl, acc[nt]);
            acc[nt] = MFMA16(al.v, bh, acc[nt]);
        }
    }

    const int bidx = i0 / SS;
    #pragma unroll
    for (int nt = 0; nt < 8; ++nt) {
        const int col = j0 + nt * 16 + ar;
        const float bb = bias[col];
        #pragma unroll
        for (int r = 0; r < 4; ++r) {
            const int rowl = w * 16 + (l >> 4) * 4 + r;
            const float val = acc[nt][r] + bb;
            if (mode == 0) {
                outf[(size_t)(i0 + rowl) * FF + col] = val;
            } else {
                const int s = (i0 - bidx * SS) + rowl;
                const size_t o = (((size_t)bidx * NH + (col >> 6)) * SS + s) * DD + (col & 63);
                if (mode == 2) {
                    outf[o] = val;
                } else {
                    ushort hv = f2bf_rne(val);
                    outhi[o] = hv;
                    outlo[o] = f2bf_rne(val - bfval(hv));
                }
            }
        }
    }
}

// ---------------------------------------------------------------------------
// Stats: per (q-tile 64, bh). 2-term QK^T, K-hi LDS dbuf. -> (m, 1/Z)
// ---------------------------------------------------------------------------
__global__ __launch_bounds__(512) void stats_kernel(
    const ushort* __restrict__ qhi, const ushort* __restrict__ qlo,
    const ushort* __restrict__ khi, float2* __restrict__ stats)
{
    __shared__ ushort KS[2][4096];
    __shared__ float redM[2][64];
    __shared__ float redS[2][64];

    const int t = threadIdx.x, w = t >> 6, l = t & 63;
    const int ar = l & 15, kgi = l >> 4, kg = kgi * 8;
    const int qs = w & 3, kh = w >> 2;
    const int qt = blockIdx.x, bh = blockIdx.y;
    const int q0 = qt * 64;
    const size_t base = (size_t)bh * SS * DD;
    const float SC = 0.125f * 1.44269504f;

    const size_t qo = base + (size_t)(q0 + qs * 16 + ar) * DD + kg;
    const bf16x8 qh0 = *(const bf16x8*)(qhi + qo);
    const bf16x8 qh1 = *(const bf16x8*)(qhi + qo + 32);
    const bf16x8 ql0 = *(const bf16x8*)(qlo + qo);
    const bf16x8 ql1 = *(const bf16x8*)(qlo + qo + 32);

    const int srow = t >> 3, sc8 = t & 7;
    const int sidx = srow * 64 + ((sc8 ^ (srow & 7)) << 3);
    const ushort* ksrc = khi + base + srow * 64 + sc8 * 8;

    uint4 rg = *(const uint4*)ksrc;
    *(uint4*)&KS[0][sidx] = rg;
    __syncthreads();

    const int sw  = ar & 7;
    const int i00 = kh * 2048 + ar * 64;
    const int i01 = i00 + 1024;
    const int s00 = (kgi ^ sw) << 3;
    const int s01 = ((4 | kgi) ^ sw) << 3;

    float m[4], s[4];
    #pragma unroll
    for (int r = 0; r < 4; ++r) { m[r] = -1e30f; s[r] = 0.f; }

    for (int kt = 0; kt < 36; ++kt) {
        const ushort* KC = &KS[kt & 1][0];
        if (kt < 35) rg = *(const uint4*)(ksrc + (size_t)(kt + 1) * 4096);
        bf16x8 b00 = *(const bf16x8*)&KC[i00 + s00];
        bf16x8 b01 = *(const bf16x8*)&KC[i00 + s01];
        bf16x8 b10 = *(const bf16x8*)&KC[i01 + s00];
        bf16x8 b11 = *(const bf16x8*)&KC[i01 + s01];
        f32x4 a0 = {0.f,0.f,0.f,0.f}, a1 = {0.f,0.f,0.f,0.f};
        a0 = MFMA16(qh0, b00, a0); a1 = MFMA16(qh0, b10, a1);
        a0 = MFMA16(qh1, b01, a0); a1 = MFMA16(qh1, b11, a1);
        a0 = MFMA16(ql0, b00, a0); a1 = MFMA16(ql0, b10, a1);
        a0 = MFMA16(ql1, b01, a0); a1 = MFMA16(ql1, b11, a1);
        #pragma unroll
        for (int r = 0; r < 4; ++r) {
            float v0 = a0[r] * SC, v1 = a1[r] * SC;
            float nm = fmaxf(m[r], fmaxf(v0, v1));
            s[r] = s[r] * exp2f(m[r] - nm) + exp2f(v0 - nm) + exp2f(v1 - nm);
            m[r] = nm;
        }
        if (kt < 35) *(uint4*)&KS[(kt & 1) ^ 1][sidx] = rg;
        __syncthreads();
    }

    #pragma unroll
    for (int off = 1; off <= 8; off <<= 1) {
        #pragma unroll
        for (int r = 0; r < 4; ++r) {
            float mo = __shfl_xor(m[r], off);
            float so = __shfl_xor(s[r], off);
            float nm = fmaxf(m[r], mo);
            s[r] = s[r] * exp2f(m[r] - nm) + so * exp2f(mo - nm);
            m[r] = nm;
        }
    }
    if (ar == 0) {
        #pragma unroll
        for (int r = 0; r < 4; ++r) {
            redM[kh][qs * 16 + kgi * 4 + r] = m[r];
            redS[kh][qs * 16 + kgi * 4 + r] = s[r];
        }
    }
    __syncthreads();
    if (t < 64) {
        float m0 = redM[0][t], m1 = redM[1][t];
        float s0 = redS[0][t], s1 = redS[1][t];
        float M  = fmaxf(m0, m1);
        float Sv = s0 * exp2f(m0 - M) + s1 * exp2f(m1 - M);
        stats[(size_t)bh * SS + q0 + t] = make_float2(M, 1.0f / Sv);
    }
}

// ---------------------------------------------------------------------------
// Fused emit+PV: per (q-tile 64, bh). K,V tiles single-buffered in LDS
// (reg-prefetch, 2 barriers/tile). QK^T 3-term -> p -> per-wave LDS bounce
// -> (a) nontemporal coalesced attn stores, (b) A-frags for PV MFMA.
// ctx reduced cross-wave at end. LDS arena 51.2KB -> 2 blocks/CU.
// ---------------------------------------------------------------------------
__global__ __launch_bounds__(512, 4) void fattn_kernel(
    const ushort* __restrict__ qhi, const ushort* __restrict__ qlo,
    const ushort* __restrict__ khi, const ushort* __restrict__ klo,
    const ushort* __restrict__ vthi, const ushort* __restrict__ vtlo,
    const float2* __restrict__ stats, float* __restrict__ attn_out,
    float* __restrict__ ctx)
{
    __shared__ __align__(16) unsigned char smem[51200];
    ushort* KH = (ushort*)smem;            // [64][64] swizzled
    ushort* KL = KH + 4096;
    ushort* VH = KL + 4096;                // [64 d][64 k] swizzled
    ushort* VL = VH + 4096;
    float*  PT = (float*)(VL + 4096);      // 8 waves x [16][36]

    const int t = threadIdx.x, w = t >> 6, l = t & 63;
    const int ar = l & 15, kgi = l >> 4;
    const int kg = kgi * 8;
    const int qs = w & 3, kh = w >> 2;

    // XCD-chunked decode: consecutive blockIdx round-robin XCDs (%8)
    const int xcd = blockIdx.x & 7;
    const int pos = blockIdx.x >> 3;       // 0..143
    const int bh  = xcd * 4 + (pos / 36);
    const int qt  = pos % 36;
    const int q0  = qt * 64;
    const int b   = bh >> 3, h = bh & 7;
    const size_t base = (size_t)bh * SS * DD;
    const float SC = 0.125f * 1.44269504f;

    // q fragments
    const size_t qo = base + (size_t)(q0 + qs * 16 + ar) * DD + kg;
    const bf16x8 qh0 = *(const bf16x8*)(qhi + qo);
    const bf16x8 qh1 = *(const bf16x8*)(qhi + qo + 32);
    const bf16x8 ql0 = *(const bf16x8*)(qlo + qo);
    const bf16x8 ql1 = *(const bf16x8*)(qlo + qo + 32);

    float m[4], inv[4];
    #pragma unroll
    for (int r = 0; r < 4; ++r) {
        float2 st = stats[(size_t)bh * SS + q0 + qs * 16 + kgi * 4 + r];
        m[r] = st.x; inv[r] = st.y;
    }

    // staging addresses
    const int srow = t >> 3, sc8 = t & 7;
    const int sidx = srow * 64 + ((sc8 ^ (srow & 7)) << 3);
    const ushort* khsrc = khi + base + srow * 64 + sc8 * 8;
    const ushort* klsrc = klo + base + srow * 64 + sc8 * 8;
    const ushort* vhsrc = vthi + ((size_t)bh * DD + srow) * SS + sc8 * 8;
    const ushort* vlsrc = vtlo + ((size_t)bh * DD + srow) * SS + sc8 * 8;

    // prologue: stage tile 0
    {
        uint4 a = *(const uint4*)khsrc;
        uint4 bq = *(const uint4*)klsrc;
        uint4 c = *(const uint4*)vhsrc;
        uint4 d = *(const uint4*)vlsrc;
        *(uint4*)&KH[sidx] = a;
        *(uint4*)&KL[sidx] = bq;
        *(uint4*)&VH[sidx] = c;
        *(uint4*)&VL[sidx] = d;
    }
    __syncthreads();

    const int sw  = ar & 7;
    const int i00 = kh * 2048 + ar * 64;
    const int i01 = i00 + 1024;
    const int s00 = (kgi ^ sw) << 3;
    const int s01 = ((4 | kgi) ^ sw) << 3;
    const int svw = ((kh * 4 + kgi) ^ sw) << 3;   // V-frag swizzled col

    float* PTw = PT + w * 576;                    // [16][36]
    float* asto = attn_out + ((size_t)bh * SS + q0 + qs * 16 + (l >> 2)) * SS
                + kh * 32 + (l & 3) * 8;

    f32x4 acc[4];
    #pragma unroll
    for (int nt = 0; nt < 4; ++nt) acc[nt] = (f32x4){0.f, 0.f, 0.f, 0.f};

    for (int kt = 0; kt < 36; ++kt) {
        // prefetch next tile into regs (non-blocking)
        uint4 rkh, rkl, rvh, rvl;
        if (kt < 35) {
            rkh = *(const uint4*)(khsrc + (size_t)(kt + 1) * 4096);
            rkl = *(const uint4*)(klsrc + (size_t)(kt + 1) * 4096);
            rvh = *(const uint4*)(vhsrc + (size_t)(kt + 1) * 64);
            rvl = *(const uint4*)(vlsrc + (size_t)(kt + 1) * 64);
        }

        // ---- QK^T (3-term) ----
        bf16x8 bh00 = *(const bf16x8*)&KH[i00 + s00];
        bf16x8 bh01 = *(const bf16x8*)&KH[i00 + s01];
        bf16x8 bl00 = *(const bf16x8*)&KL[i00 + s00];
        bf16x8 bl01 = *(const bf16x8*)&KL[i00 + s01];
        bf16x8 bh10 = *(const bf16x8*)&KH[i01 + s00];
        bf16x8 bh11 = *(const bf16x8*)&KH[i01 + s01];
        bf16x8 bl10 = *(const bf16x8*)&KL[i01 + s00];
        bf16x8 bl11 = *(const bf16x8*)&KL[i01 + s01];
        f32x4 a0 = {0.f,0.f,0.f,0.f}, a1 = {0.f,0.f,0.f,0.f};
        __builtin_amdgcn_s_setprio(1);
        a0 = MFMA16(qh0, bh00, a0); a1 = MFMA16(qh0, bh10, a1);
        a0 = MFMA16(qh0, bl00, a0); a1 = MFMA16(qh0, bl10, a1);
        a0 = MFMA16(ql0, bh00, a0); a1 = MFMA16(ql0, bh10, a1);
        a0 = MFMA16(qh1, bh01, a0); a1 = MFMA16(qh1, bh11, a1);
        a0 = MFMA16(qh1, bl01, a0); a1 = MFMA16(qh1, bl11, a1);
        a0 = MFMA16(ql1, bh01, a0); a1 = MFMA16(ql1, bh11, a1);
        __builtin_amdgcn_s_setprio(0);

        // ---- softmax -> p into per-wave LDS tile ----
        #pragma unroll
        for (int r = 0; r < 4; ++r) {
            const int row = kgi * 4 + r;
            float p0 = exp2f(a0[r] * SC - m[r]) * inv[r];
            float p1 = exp2f(a1[r] * SC - m[r]) * inv[r];
            PTw[row * 36 + ar]      = p0;
            PTw[row * 36 + 16 + ar] = p1;
        }

        // ---- coalesced nontemporal attn store (transposed read) ----
        {
            const float* psr = PTw + (l >> 2) * 36 + (l & 3) * 8;
            f32x4 sv0 = *(const f32x4*)psr;
            f32x4 sv1 = *(const f32x4*)(psr + 4);
            f32x4* dst = (f32x4*)(asto + (size_t)kt * 64);
            __builtin_nontemporal_store(sv0, dst);
            __builtin_nontemporal_store(sv1, dst + 1);
        }

        // ---- PV: A-frag from LDS, split hi/lo; B = V^T frags ----
        {
            const float* par = PTw + ar * 36 + kg;
            f32x4 pf0 = *(const f32x4*)par;
            f32x4 pf1 = *(const f32x4*)(par + 4);
            union { uint u[4]; bf16x8 v; } pah, pal;
            ushort hh[8]; float rr[8];
            #pragma unroll
            for (int j = 0; j < 4; ++j) {
                hh[j]     = f2bf_rne(pf0[j]); rr[j]     = pf0[j] - bfval(hh[j]);
                hh[4 + j] = f2bf_rne(pf1[j]); rr[4 + j] = pf1[j] - bfval(hh[4 + j]);
            }
            #pragma unroll
            for (int j = 0; j < 4; ++j) {
                pah.u[j] = (uint)hh[2*j] | ((uint)hh[2*j+1] << 16);
                pal.u[j] = (uint)f2bf_rne(rr[2*j]) | ((uint)f2bf_rne(rr[2*j+1]) << 16);
            }
            __builtin_amdgcn_s_setprio(1);
            #pragma unroll
            for (int nt = 0; nt < 4; ++nt) {
                const int vfi = (nt * 16 + ar) * 64 + svw;
                bf16x8 vh = *(const bf16x8*)&VH[vfi];
                bf16x8 vl = *(const bf16x8*)&VL[vfi];
                acc[nt] = MFMA16(pah.v, vh, acc[nt]);
                acc[nt] = MFMA16(pah.v, vl, acc[nt]);
                acc[nt] = MFMA16(pal.v, vh, acc[nt]);
            }
            __builtin_amdgcn_s_setprio(0);
        }

        __syncthreads();                 // all LDS reads of this tile done
        if (kt < 35) {
            *(uint4*)&KH[sidx] = rkh;
            *(uint4*)&KL[sidx] = rkl;
            *(uint4*)&VH[sidx] = rvh;
            *(uint4*)&VL[sidx] = rvl;
        }
        __syncthreads();                 // staged tile visible
    }

    // ---- cross-wave ctx reduction (kh pairs) ----
    float* SCR = (float*)smem;           // [8][16][68] = 34,816B
    #pragma unroll
    for (int nt = 0; nt < 4; ++nt) {
        #pragma unroll
        for (int r = 0; r < 4; ++r)
            SCR[w * 1088 + (kgi * 4 + r) * 68 + nt * 16 + ar] = acc[nt][r];
    }
    __syncthreads();
    {
        const int rrow = t >> 3;             // 0..63
        const int dg   = (t & 7) * 8;
        const int rqs  = rrow >> 4, rl = rrow & 15;
        const float* s0p = SCR + rqs * 1088 + rl * 68 + dg;
        const float* s1p = s0p + 4 * 1088;
        f32x4 o0, o1;
        #pragma unroll
        for (int j = 0; j < 4; ++j) o0[j] = s0p[j] + s1p[j];
        #pragma unroll
        for (int j = 0; j < 4; ++j) o1[j] = s0p[4 + j] + s1p[4 + j];
        float* cdst = ctx + ((size_t)b * SS + q0 + rrow) * FF + h * DD + dg;
        *(f32x4*)cdst = o0;
        *(f32x4*)(cdst + 4) = o1;
    }
}

extern "C" void kernel_launch(void* const* d_in, const int* in_sizes, int n_in,
                              void* d_out, int out_size, void* d_ws, size_t ws_size,
                              hipStream_t stream) {
    (void)in_sizes; (void)n_in; (void)out_size; (void)ws_size;
    const float* query = (const float*)d_in[0];
    const float* value = (const float*)d_in[1];
    const float* keys  = (const float*)d_in[2];
    const float* wq_w  = (const float*)d_in[3];
    const float* wq_b  = (const float*)d_in[4];
    const float* wk_w  = (const float*)d_in[5];
    const float* wk_b  = (const float*)d_in[6];
    const float* wv_w  = (const float*)d_in[7];
    const float* wv_b  = (const float*)d_in[8];
    const float* wo_w  = (const float*)d_in[9];
    const float* wo_b  = (const float*)d_in[10];

    float* out  = (float*)d_out;
    float* attn = out + (size_t)BB * SS * FF;

    const size_t NQ = (size_t)BB * NH * SS * DD;   // 4,718,592
    ushort* qhi    = (ushort*)d_ws;
    ushort* qlo    = qhi + NQ;
    ushort* khi    = qlo + NQ;
    ushort* klo    = khi + NQ;
    ushort* vthi   = klo + NQ;
    ushort* vtlo   = vthi + NQ;
    float*  vstage = (float*)(vtlo + NQ);          // NQ f32; later ctx
    ushort* wthi   = (ushort*)(vstage + NQ);
    ushort* wtlo   = wthi + (size_t)FF * FF;
    float2* stats  = (float2*)(wtlo + (size_t)FF * FF);

    dim3 gwt(FF / 64, FF / 64);
    dim3 gproj(BSR / 64, FF / 128);
    dim3 gvt(SS / 64, BB * NH);
    dim3 gse(SS / 64, BB * NH);

    wtsplit_kernel<<<gwt, 256, 0, stream>>>(wq_w, wthi, wtlo);
    proj_mfma<<<gproj, 256, 0, stream>>>(query, wthi, wtlo, wq_b, nullptr, qhi, qlo, 1);
    wtsplit_kernel<<<gwt, 256, 0, stream>>>(wk_w, wthi, wtlo);
    proj_mfma<<<gproj, 256, 0, stream>>>(keys, wthi, wtlo, wk_b, nullptr, khi, klo, 1);
    wtsplit_kernel<<<gwt, 256, 0, stream>>>(wv_w, wthi, wtlo);
    proj_mfma<<<gproj, 256, 0, stream>>>(value, wthi, wtlo, wv_b, vstage, nullptr, nullptr, 2);
    vtsplit_kernel<<<gvt, 256, 0, stream>>>(vstage, vthi, vtlo);

    stats_kernel<<<gse, 512, 0, stream>>>(qhi, qlo, khi, stats);
    fattn_kernel<<<36 * 32, 512, 0, stream>>>(qhi, qlo, khi, klo, vthi, vtlo,
                                              stats, attn, vstage);

    wtsplit_kernel<<<gwt, 256, 0, stream>>>(wo_w, wthi, wtlo);
    proj_mfma<<<gproj, 256, 0, stream>>>(vstage, wthi, wtlo, wo_b, out, nullptr, nullptr, 0);
}

// Round 6
// 727.187 us; speedup vs baseline: 1.7806x; 1.1716x over previous
//
#include <hip/hip_runtime.h>
#include <cstddef>

#define BB 4
#define SS 2304      // 48*48
#define FF 512
#define NH 8
#define DD 64
#define BSR (BB*SS)  // 9216 rows

typedef __attribute__((ext_vector_type(8))) short bf16x8;
typedef __attribute__((ext_vector_type(4))) float f32x4;
#define MFMA16(a,b,c) __builtin_amdgcn_mfma_f32_16x16x32_bf16((a),(b),(c),0,0,0)

__device__ __forceinline__ ushort f2bf_rne(float x) {
    uint u = __float_as_uint(x);
    uint r = u + 0x7fffu + ((u >> 16) & 1u);
    return (ushort)(r >> 16);
}
__device__ __forceinline__ float bfval(ushort h) {
    return __uint_as_float((uint)h << 16);
}

// ---------------------------------------------------------------------------
// Weight transpose+split: W[k][n] (512x512 f32) -> Wt{hi,lo}[n][k] bf16
// ---------------------------------------------------------------------------
__global__ __launch_bounds__(256) void wtsplit_kernel(
    const float* __restrict__ w, ushort* __restrict__ whi, ushort* __restrict__ wlo)
{
    __shared__ __align__(16) float tile[64][68];
    const int t  = threadIdx.x;
    const int kt = blockIdx.x;
    const int nt = blockIdx.y;
    {
        const int r  = t >> 2;
        const int cg = (t & 3) * 16;
        const float* src = w + (size_t)(kt * 64 + r) * FF + nt * 64 + cg;
        #pragma unroll
        for (int j = 0; j < 4; ++j)
            *(float4*)&tile[r][cg + 4 * j] = *(const float4*)(src + 4 * j);
    }
    __syncthreads();
    {
        const int n  = t >> 2;
        const int kg = (t & 3) * 16;
        union { ushort s[16]; uint4 q[2]; } H, L;
        #pragma unroll
        for (int j = 0; j < 16; ++j) {
            float x = tile[kg + j][n];
            ushort hh = f2bf_rne(x);
            H.s[j] = hh;
            L.s[j] = f2bf_rne(x - bfval(hh));
        }
        size_t off = (size_t)(nt * 64 + n) * FF + kt * 64 + kg;
        *(uint4*)(whi + off)     = H.q[0];
        *(uint4*)(whi + off + 8) = H.q[1];
        *(uint4*)(wlo + off)     = L.q[0];
        *(uint4*)(wlo + off + 8) = L.q[1];
    }
}

// ---------------------------------------------------------------------------
// V transpose+split: v[bh][s][d] f32 -> vt{hi,lo}[bh][d][s] bf16
// ---------------------------------------------------------------------------
__global__ __launch_bounds__(256) void vtsplit_kernel(
    const float* __restrict__ v, ushort* __restrict__ vthi, ushort* __restrict__ vtlo)
{
    __shared__ __align__(16) float tile[64][68];
    const int t  = threadIdx.x;
    const int st = blockIdx.x;
    const int bh = blockIdx.y;
    {
        const int r  = t >> 2;
        const int cg = (t & 3) * 16;
        const float* src = v + ((size_t)bh * SS + st * 64 + r) * DD + cg;
        #pragma unroll
        for (int j = 0; j < 4; ++j)
            *(float4*)&tile[r][cg + 4 * j] = *(const float4*)(src + 4 * j);
    }
    __syncthreads();
    {
        const int d  = t >> 2;
        const int sg = (t & 3) * 16;
        union { ushort s[16]; uint4 q[2]; } H, L;
        #pragma unroll
        for (int j = 0; j < 16; ++j) {
            float x = tile[sg + j][d];
            ushort hh = f2bf_rne(x);
            H.s[j] = hh;
            L.s[j] = f2bf_rne(x - bfval(hh));
        }
        size_t off = ((size_t)bh * DD + d) * SS + st * 64 + sg;
        *(uint4*)(vthi + off)     = H.q[0];
        *(uint4*)(vthi + off + 8) = H.q[1];
        *(uint4*)(vtlo + off)     = L.q[0];
        *(uint4*)(vtlo + off + 8) = L.q[1];
    }
}

// ---------------------------------------------------------------------------
// Projection GEMM via split-bf16 MFMA: out = X @ W + b.  Tile 64x128.
// ---------------------------------------------------------------------------
__global__ __launch_bounds__(256) void proj_mfma(
    const float* __restrict__ X, const ushort* __restrict__ wth,
    const ushort* __restrict__ wtl, const float* __restrict__ bias,
    float* __restrict__ outf, ushort* __restrict__ outhi,
    ushort* __restrict__ outlo, int mode)
{
    const int t  = threadIdx.x, w = t >> 6, l = t & 63;
    const int ar = l & 15, kg = (l >> 4) * 8;
    const int i0 = blockIdx.x * 64, j0 = blockIdx.y * 128;
    const int arow = i0 + w * 16 + ar;

    f32x4 acc[8];
    #pragma unroll
    for (int nt = 0; nt < 8; ++nt) acc[nt] = (f32x4){0.f, 0.f, 0.f, 0.f};

    for (int kk = 0; kk < FF; kk += 32) {
        const float* xr = X + (size_t)arow * FF + kk + kg;
        float4 f0 = *(const float4*)xr;
        float4 f1 = *(const float4*)(xr + 4);
        ushort h0 = f2bf_rne(f0.x), h1 = f2bf_rne(f0.y), h2 = f2bf_rne(f0.z), h3 = f2bf_rne(f0.w);
        ushort h4 = f2bf_rne(f1.x), h5 = f2bf_rne(f1.y), h6 = f2bf_rne(f1.z), h7 = f2bf_rne(f1.w);
        union { uint u[4]; bf16x8 v; } ah, al;
        ah.u[0] = (uint)h0 | ((uint)h1 << 16);
        ah.u[1] = (uint)h2 | ((uint)h3 << 16);
        ah.u[2] = (uint)h4 | ((uint)h5 << 16);
        ah.u[3] = (uint)h6 | ((uint)h7 << 16);
        al.u[0] = (uint)f2bf_rne(f0.x - bfval(h0)) | ((uint)f2bf_rne(f0.y - bfval(h1)) << 16);
        al.u[1] = (uint)f2bf_rne(f0.z - bfval(h2)) | ((uint)f2bf_rne(f0.w - bfval(h3)) << 16);
        al.u[2] = (uint)f2bf_rne(f1.x - bfval(h4)) | ((uint)f2bf_rne(f1.y - bfval(h5)) << 16);
        al.u[3] = (uint)f2bf_rne(f1.z - bfval(h6)) | ((uint)f2bf_rne(f1.w - bfval(h7)) << 16);
        #pragma unroll
        for (int nt = 0; nt < 8; ++nt) {
            const size_t wo = (size_t)(j0 + nt * 16 + ar) * FF + kk + kg;
            bf16x8 bh = *(const bf16x8*)(wth + wo);
            bf16x8 bl = *(const bf16x8*)(wtl + wo);
            acc[nt] = MFMA16(ah.v, bh, acc[nt]);
            acc[nt] = MFMA16(ah.v, bl, acc[nt]);
            acc[nt] = MFMA16(al.v, bh, acc[nt]);
        }
    }

    const int bidx = i0 / SS;
    #pragma unroll
    for (int nt = 0; nt < 8; ++nt) {
        const int col = j0 + nt * 16 + ar;
        const float bb = bias[col];
        #pragma unroll
        for (int r = 0; r < 4; ++r) {
            const int rowl = w * 16 + (l >> 4) * 4 + r;
            const float val = acc[nt][r] + bb;
            if (mode == 0) {
                outf[(size_t)(i0 + rowl) * FF + col] = val;
            } else {
                const int s = (i0 - bidx * SS) + rowl;
                const size_t o = (((size_t)bidx * NH + (col >> 6)) * SS + s) * DD + (col & 63);
                if (mode == 2) {
                    outf[o] = val;
                } else {
                    ushort hv = f2bf_rne(val);
                    outhi[o] = hv;
                    outlo[o] = f2bf_rne(val - bfval(hv));
                }
            }
        }
    }
}

// ---------------------------------------------------------------------------
// Fused attention: per (q-tile 64, bh) block, 512 thr.
// Pass 1: QK^T 2-term, K-hi LDS double-buffered (1 barrier/tile), online
//         (m,s) in registers -> cross-lane/cross-wave merge in LDS.
// Pass 2: QK^T 3-term (K hi/lo dbuf) -> softmax -> per-wave LDS p tile ->
//         nontemporal coalesced attn stores + PV MFMA (V single-buffered).
// LDS 67.6KB -> 2 blocks/CU.
// ---------------------------------------------------------------------------
__global__ __launch_bounds__(512, 4) void fattn_kernel(
    const ushort* __restrict__ qhi, const ushort* __restrict__ qlo,
    const ushort* __restrict__ khi, const ushort* __restrict__ klo,
    const ushort* __restrict__ vthi, const ushort* __restrict__ vtlo,
    float* __restrict__ attn_out, float* __restrict__ ctx)
{
    __shared__ __align__(16) unsigned char smem[67584];
    ushort* KH0 = (ushort*)smem;          // [64][64] swizzled, dbuf
    ushort* KH1 = KH0 + 4096;
    ushort* KL0 = KH1 + 4096;
    ushort* KL1 = KL0 + 4096;
    ushort* VH  = KL1 + 4096;             // [64 d][64 k] swizzled, single
    ushort* VL  = VH + 4096;
    float*  PT  = (float*)(VL + 4096);    // 8 waves x [16][36] f32
    float*  redM = PT;                    // pass-1 overlay [2][64]
    float*  redS = PT + 128;

    const int t = threadIdx.x, w = t >> 6, l = t & 63;
    const int ar = l & 15, kgi = l >> 4;
    const int kg = kgi * 8;
    const int qs = w & 3, kh = w >> 2;

    // XCD-chunked decode (grid 1152 = 8 XCDs x 144)
    const int xcd = blockIdx.x & 7;
    const int pos = blockIdx.x >> 3;       // 0..143
    const int bh  = xcd * 4 + (pos / 36);
    const int qt  = pos % 36;
    const int q0  = qt * 64;
    const int b   = bh >> 3, h = bh & 7;
    const size_t base = (size_t)bh * SS * DD;
    const float SC = 0.125f * 1.44269504f;

    // q fragments (persist across both passes)
    const size_t qo = base + (size_t)(q0 + qs * 16 + ar) * DD + kg;
    const bf16x8 qh0 = *(const bf16x8*)(qhi + qo);
    const bf16x8 qh1 = *(const bf16x8*)(qhi + qo + 32);
    const bf16x8 ql0 = *(const bf16x8*)(qlo + qo);
    const bf16x8 ql1 = *(const bf16x8*)(qlo + qo + 32);

    // staging addresses
    const int srow = t >> 3, sc8 = t & 7;
    const int sidx = srow * 64 + ((sc8 ^ (srow & 7)) << 3);
    const ushort* khsrc = khi + base + srow * 64 + sc8 * 8;
    const ushort* klsrc = klo + base + srow * 64 + sc8 * 8;
    const ushort* vhsrc = vthi + ((size_t)bh * DD + srow) * SS + sc8 * 8;
    const ushort* vlsrc = vtlo + ((size_t)bh * DD + srow) * SS + sc8 * 8;

    // fragment read offsets (swizzled)
    const int sw  = ar & 7;
    const int i00 = kh * 2048 + ar * 64;
    const int i01 = i00 + 1024;
    const int s00 = (kgi ^ sw) << 3;
    const int s01 = ((4 | kgi) ^ sw) << 3;
    const int svw = ((kh * 4 + kgi) ^ sw) << 3;

    // ================= Pass 1: stats (2-term, K-hi dbuf, 1 barrier/tile) ===
    float m_[4], s_[4];
    #pragma unroll
    for (int r = 0; r < 4; ++r) { m_[r] = -1e30f; s_[r] = 0.f; }
    {
        uint4 rk = *(const uint4*)khsrc;
        *(uint4*)&KH0[sidx] = rk;
        __syncthreads();
        for (int kt = 0; kt < 36; ++kt) {
            if (kt < 35) rk = *(const uint4*)(khsrc + (size_t)(kt + 1) * 4096);
            const ushort* KC = (kt & 1) ? KH1 : KH0;
            bf16x8 b00 = *(const bf16x8*)&KC[i00 + s00];
            bf16x8 b01 = *(const bf16x8*)&KC[i00 + s01];
            bf16x8 b10 = *(const bf16x8*)&KC[i01 + s00];
            bf16x8 b11 = *(const bf16x8*)&KC[i01 + s01];
            f32x4 a0 = {0.f,0.f,0.f,0.f}, a1 = {0.f,0.f,0.f,0.f};
            __builtin_amdgcn_s_setprio(1);
            a0 = MFMA16(qh0, b00, a0); a1 = MFMA16(qh0, b10, a1);
            a0 = MFMA16(qh1, b01, a0); a1 = MFMA16(qh1, b11, a1);
            a0 = MFMA16(ql0, b00, a0); a1 = MFMA16(ql0, b10, a1);
            a0 = MFMA16(ql1, b01, a0); a1 = MFMA16(ql1, b11, a1);
            __builtin_amdgcn_s_setprio(0);
            #pragma unroll
            for (int r = 0; r < 4; ++r) {
                float v0 = a0[r] * SC, v1 = a1[r] * SC;
                float nm = fmaxf(m_[r], fmaxf(v0, v1));
                s_[r] = s_[r] * exp2f(m_[r] - nm) + exp2f(v0 - nm) + exp2f(v1 - nm);
                m_[r] = nm;
            }
            if (kt < 35) {
                ushort* KN = (kt & 1) ? KH0 : KH1;
                *(uint4*)&KN[sidx] = rk;
            }
            __syncthreads();
        }
    }
    #pragma unroll
    for (int off = 1; off <= 8; off <<= 1) {
        #pragma unroll
        for (int r = 0; r < 4; ++r) {
            float mo = __shfl_xor(m_[r], off);
            float so = __shfl_xor(s_[r], off);
            float nm = fmaxf(m_[r], mo);
            s_[r] = s_[r] * exp2f(m_[r] - nm) + so * exp2f(mo - nm);
            m_[r] = nm;
        }
    }
    if (ar == 0) {
        #pragma unroll
        for (int r = 0; r < 4; ++r) {
            redM[kh * 64 + qs * 16 + kgi * 4 + r] = m_[r];
            redS[kh * 64 + qs * 16 + kgi * 4 + r] = s_[r];
        }
    }
    __syncthreads();
    float mf[4], inv[4];
    #pragma unroll
    for (int r = 0; r < 4; ++r) {
        const int idx = qs * 16 + kgi * 4 + r;
        float m0 = redM[idx], m1 = redM[64 + idx];
        float s0 = redS[idx], s1 = redS[64 + idx];
        float M  = fmaxf(m0, m1);
        float Sv = s0 * exp2f(m0 - M) + s1 * exp2f(m1 - M);
        mf[r]  = M;
        inv[r] = 1.0f / Sv;
    }

    // ================= Pass 2: emit + PV =================
    float* PTw = PT + w * 576;                    // [16][36]
    float* asto = attn_out + ((size_t)bh * SS + q0 + qs * 16 + (l >> 2)) * SS
                + kh * 32 + (l & 3) * 8;

    f32x4 acc[4];
    #pragma unroll
    for (int nt = 0; nt < 4; ++nt) acc[nt] = (f32x4){0.f, 0.f, 0.f, 0.f};

    // prologue: stage tile 0 (K into buf0, V single)
    {
        uint4 a = *(const uint4*)khsrc;
        uint4 bq = *(const uint4*)klsrc;
        uint4 c = *(const uint4*)vhsrc;
        uint4 d = *(const uint4*)vlsrc;
        *(uint4*)&KH0[sidx] = a;
        *(uint4*)&KL0[sidx] = bq;
        *(uint4*)&VH[sidx]  = c;
        *(uint4*)&VL[sidx]  = d;
    }
    __syncthreads();

    for (int kt = 0; kt < 36; ++kt) {
        uint4 rkh, rkl, rvh, rvl;
        if (kt < 35) {
            rkh = *(const uint4*)(khsrc + (size_t)(kt + 1) * 4096);
            rkl = *(const uint4*)(klsrc + (size_t)(kt + 1) * 4096);
            rvh = *(const uint4*)(vhsrc + (size_t)(kt + 1) * 64);
            rvl = *(const uint4*)(vlsrc + (size_t)(kt + 1) * 64);
        }
        const ushort* KHc = (kt & 1) ? KH1 : KH0;
        const ushort* KLc = (kt & 1) ? KL1 : KL0;

        // ---- QK^T (3-term) ----
        bf16x8 bh00 = *(const bf16x8*)&KHc[i00 + s00];
        bf16x8 bh01 = *(const bf16x8*)&KHc[i00 + s01];
        bf16x8 bl00 = *(const bf16x8*)&KLc[i00 + s00];
        bf16x8 bl01 = *(const bf16x8*)&KLc[i00 + s01];
        bf16x8 bh10 = *(const bf16x8*)&KHc[i01 + s00];
        bf16x8 bh11 = *(const bf16x8*)&KHc[i01 + s01];
        bf16x8 bl10 = *(const bf16x8*)&KLc[i01 + s00];
        bf16x8 bl11 = *(const bf16x8*)&KLc[i01 + s01];
        f32x4 a0 = {0.f,0.f,0.f,0.f}, a1 = {0.f,0.f,0.f,0.f};
        __builtin_amdgcn_s_setprio(1);
        a0 = MFMA16(qh0, bh00, a0); a1 = MFMA16(qh0, bh10, a1);
        a0 = MFMA16(qh0, bl00, a0); a1 = MFMA16(qh0, bl10, a1);
        a0 = MFMA16(ql0, bh00, a0); a1 = MFMA16(ql0, bh10, a1);
        a0 = MFMA16(qh1, bh01, a0); a1 = MFMA16(qh1, bh11, a1);
        a0 = MFMA16(qh1, bl01, a0); a1 = MFMA16(qh1, bl11, a1);
        a0 = MFMA16(ql1, bh01, a0); a1 = MFMA16(ql1, bh11, a1);
        __builtin_amdgcn_s_setprio(0);

        // ---- softmax -> p into per-wave LDS tile ----
        #pragma unroll
        for (int r = 0; r < 4; ++r) {
            const int row = kgi * 4 + r;
            float p0 = exp2f(a0[r] * SC - mf[r]) * inv[r];
            float p1 = exp2f(a1[r] * SC - mf[r]) * inv[r];
            PTw[row * 36 + ar]      = p0;
            PTw[row * 36 + 16 + ar] = p1;
        }

        // ---- coalesced nontemporal attn store (transposed read) ----
        {
            const float* psr = PTw + (l >> 2) * 36 + (l & 3) * 8;
            f32x4 sv0 = *(const f32x4*)psr;
            f32x4 sv1 = *(const f32x4*)(psr + 4);
            f32x4* dst = (f32x4*)(asto + (size_t)kt * 64);
            __builtin_nontemporal_store(sv0, dst);
            __builtin_nontemporal_store(sv1, dst + 1);
        }

        // ---- PV: A-frag from LDS, split hi/lo; B = V^T frags ----
        {
            const float* par = PTw + ar * 36 + kg;
            f32x4 pf0 = *(const f32x4*)par;
            f32x4 pf1 = *(const f32x4*)(par + 4);
            union { uint u[4]; bf16x8 v; } pah, pal;
            ushort hh[8]; float rr[8];
            #pragma unroll
            for (int j = 0; j < 4; ++j) {
                hh[j]     = f2bf_rne(pf0[j]); rr[j]     = pf0[j] - bfval(hh[j]);
                hh[4 + j] = f2bf_rne(pf1[j]); rr[4 + j] = pf1[j] - bfval(hh[4 + j]);
            }
            #pragma unroll
            for (int j = 0; j < 4; ++j) {
                pah.u[j] = (uint)hh[2*j] | ((uint)hh[2*j+1] << 16);
                pal.u[j] = (uint)f2bf_rne(rr[2*j]) | ((uint)f2bf_rne(rr[2*j+1]) << 16);
            }
            __builtin_amdgcn_s_setprio(1);
            #pragma unroll
            for (int nt = 0; nt < 4; ++nt) {
                const int vfi = (nt * 16 + ar) * 64 + svw;
                bf16x8 vh = *(const bf16x8*)&VH[vfi];
                bf16x8 vl = *(const bf16x8*)&VL[vfi];
                acc[nt] = MFMA16(pah.v, vh, acc[nt]);
                acc[nt] = MFMA16(pah.v, vl, acc[nt]);
                acc[nt] = MFMA16(pal.v, vh, acc[nt]);
            }
            __builtin_amdgcn_s_setprio(0);
        }

        // K double-buffer write is safe before the barrier
        if (kt < 35) {
            ushort* KHN = (kt & 1) ? KH0 : KH1;
            ushort* KLN = (kt & 1) ? KL0 : KL1;
            *(uint4*)&KHN[sidx] = rkh;
            *(uint4*)&KLN[sidx] = rkl;
        }
        __syncthreads();                 // V reads + K writes done
        if (kt < 35) {
            *(uint4*)&VH[sidx] = rvh;
            *(uint4*)&VL[sidx] = rvl;
            __syncthreads();             // V visible
        }
    }

    // ---- cross-wave ctx reduction (kh pairs) ----
    float* SCR = (float*)smem;           // [8][16][68] = 34,816B
    #pragma unroll
    for (int nt = 0; nt < 4; ++nt) {
        #pragma unroll
        for (int r = 0; r < 4; ++r)
            SCR[w * 1088 + (kgi * 4 + r) * 68 + nt * 16 + ar] = acc[nt][r];
    }
    __syncthreads();
    {
        const int rrow = t >> 3;             // 0..63
        const int dg   = (t & 7) * 8;
        const int rqs  = rrow >> 4, rl = rrow & 15;
        const float* s0p = SCR + rqs * 1088 + rl * 68 + dg;
        const float* s1p = s0p + 4 * 1088;
        f32x4 o0, o1;
        #pragma unroll
        for (int j = 0; j < 4; ++j) o0[j] = s0p[j] + s1p[j];
        #pragma unroll
        for (int j = 0; j < 4; ++j) o1[j] = s0p[4 + j] + s1p[4 + j];
        float* cdst = ctx + ((size_t)b * SS + q0 + rrow) * FF + h * DD + dg;
        *(f32x4*)cdst = o0;
        *(f32x4*)(cdst + 4) = o1;
    }
}

extern "C" void kernel_launch(void* const* d_in, const int* in_sizes, int n_in,
                              void* d_out, int out_size, void* d_ws, size_t ws_size,
                              hipStream_t stream) {
    (void)in_sizes; (void)n_in; (void)out_size; (void)ws_size;
    const float* query = (const float*)d_in[0];
    const float* value = (const float*)d_in[1];
    const float* keys  = (const float*)d_in[2];
    const float* wq_w  = (const float*)d_in[3];
    const float* wq_b  = (const float*)d_in[4];
    const float* wk_w  = (const float*)d_in[5];
    const float* wk_b  = (const float*)d_in[6];
    const float* wv_w  = (const float*)d_in[7];
    const float* wv_b  = (const float*)d_in[8];
    const float* wo_w  = (const float*)d_in[9];
    const float* wo_b  = (const float*)d_in[10];

    float* out  = (float*)d_out;
    float* attn = out + (size_t)BB * SS * FF;

    const size_t NQ = (size_t)BB * NH * SS * DD;   // 4,718,592
    ushort* qhi    = (ushort*)d_ws;
    ushort* qlo    = qhi + NQ;
    ushort* khi    = qlo + NQ;
    ushort* klo    = khi + NQ;
    ushort* vthi   = klo + NQ;
    ushort* vtlo   = vthi + NQ;
    float*  vstage = (float*)(vtlo + NQ);          // NQ f32; later ctx
    ushort* wthi   = (ushort*)(vstage + NQ);
    ushort* wtlo   = wthi + (size_t)FF * FF;

    dim3 gwt(FF / 64, FF / 64);
    dim3 gproj(BSR / 64, FF / 128);
    dim3 gvt(SS / 64, BB * NH);

    wtsplit_kernel<<<gwt, 256, 0, stream>>>(wq_w, wthi, wtlo);
    proj_mfma<<<gproj, 256, 0, stream>>>(query, wthi, wtlo, wq_b, nullptr, qhi, qlo, 1);
    wtsplit_kernel<<<gwt, 256, 0, stream>>>(wk_w, wthi, wtlo);
    proj_mfma<<<gproj, 256, 0, stream>>>(keys, wthi, wtlo, wk_b, nullptr, khi, klo, 1);
    wtsplit_kernel<<<gwt, 256, 0, stream>>>(wv_w, wthi, wtlo);
    proj_mfma<<<gproj, 256, 0, stream>>>(value, wthi, wtlo, wv_b, vstage, nullptr, nullptr, 2);
    vtsplit_kernel<<<gvt, 256, 0, stream>>>(vstage, vthi, vtlo);

    fattn_kernel<<<36 * 32, 512, 0, stream>>>(qhi, qlo, khi, klo, vthi, vtlo,
                                              attn, vstage);

    wtsplit_kernel<<<gwt, 256, 0, stream>>>(wo_w, wthi, wtlo);
    proj_mfma<<<gproj, 256, 0, stream>>>(vstage, wthi, wtlo, wo_b, out, nullptr, nullptr, 0);
}

// Round 7
// 640.260 us; speedup vs baseline: 2.0223x; 1.1358x over previous
//
#include <hip/hip_runtime.h>
#include <cstddef>

#define BB 4
#define SS 2304      // 48*48
#define FF 512
#define NH 8
#define DD 64
#define BSR (BB*SS)  // 9216 rows

typedef __attribute__((ext_vector_type(8))) short bf16x8;
typedef __attribute__((ext_vector_type(4))) float f32x4;
#define MFMA16(a,b,c) __builtin_amdgcn_mfma_f32_16x16x32_bf16((a),(b),(c),0,0,0)

__device__ __forceinline__ ushort f2bf_rne(float x) {
    uint u = __float_as_uint(x);
    uint r = u + 0x7fffu + ((u >> 16) & 1u);
    return (ushort)(r >> 16);
}
__device__ __forceinline__ float bfval(ushort h) {
    return __uint_as_float((uint)h << 16);
}

// ---------------------------------------------------------------------------
// All 4 weight transpose+splits in one launch: W[k][n] -> Wt{hi,lo}[n][k]
// blockIdx.z selects the weight.
// ---------------------------------------------------------------------------
__global__ __launch_bounds__(256) void wtsplit_all(
    const float* __restrict__ w0, const float* __restrict__ w1,
    const float* __restrict__ w2, const float* __restrict__ w3,
    ushort* __restrict__ whi_all, ushort* __restrict__ wlo_all)
{
    __shared__ __align__(16) float tile[64][68];
    const int z = blockIdx.z;
    const float* w = (z == 0) ? w0 : (z == 1) ? w1 : (z == 2) ? w2 : w3;
    ushort* whi = whi_all + (size_t)z * FF * FF;
    ushort* wlo = wlo_all + (size_t)z * FF * FF;

    const int t  = threadIdx.x;
    const int kt = blockIdx.x;
    const int nt = blockIdx.y;
    {
        const int r  = t >> 2;
        const int cg = (t & 3) * 16;
        const float* src = w + (size_t)(kt * 64 + r) * FF + nt * 64 + cg;
        #pragma unroll
        for (int j = 0; j < 4; ++j)
            *(float4*)&tile[r][cg + 4 * j] = *(const float4*)(src + 4 * j);
    }
    __syncthreads();
    {
        const int n  = t >> 2;
        const int kg = (t & 3) * 16;
        union { ushort s[16]; uint4 q[2]; } H, L;
        #pragma unroll
        for (int j = 0; j < 16; ++j) {
            float x = tile[kg + j][n];
            ushort hh = f2bf_rne(x);
            H.s[j] = hh;
            L.s[j] = f2bf_rne(x - bfval(hh));
        }
        size_t off = (size_t)(nt * 64 + n) * FF + kt * 64 + kg;
        *(uint4*)(whi + off)     = H.q[0];
        *(uint4*)(whi + off + 8) = H.q[1];
        *(uint4*)(wlo + off)     = L.q[0];
        *(uint4*)(wlo + off + 8) = L.q[1];
    }
}

// ---------------------------------------------------------------------------
// V transpose (hi only): v[bh][s][d] f32 -> vthi[bh][d][s] bf16
// ---------------------------------------------------------------------------
__global__ __launch_bounds__(256) void vtsplit_kernel(
    const float* __restrict__ v, ushort* __restrict__ vthi)
{
    __shared__ __align__(16) float tile[64][68];
    const int t  = threadIdx.x;
    const int st = blockIdx.x;
    const int bh = blockIdx.y;
    {
        const int r  = t >> 2;
        const int cg = (t & 3) * 16;
        const float* src = v + ((size_t)bh * SS + st * 64 + r) * DD + cg;
        #pragma unroll
        for (int j = 0; j < 4; ++j)
            *(float4*)&tile[r][cg + 4 * j] = *(const float4*)(src + 4 * j);
    }
    __syncthreads();
    {
        const int d  = t >> 2;
        const int sg = (t & 3) * 16;
        union { ushort s[16]; uint4 q[2]; } H;
        #pragma unroll
        for (int j = 0; j < 16; ++j) H.s[j] = f2bf_rne(tile[sg + j][d]);
        size_t off = ((size_t)bh * DD + d) * SS + st * 64 + sg;
        *(uint4*)(vthi + off)     = H.q[0];
        *(uint4*)(vthi + off + 8) = H.q[1];
    }
}

// ---------------------------------------------------------------------------
// Fused QKV projection: z=0 -> q (3-term, hi+lo out), z=1 -> k (3-term,
// hi+lo out), z=2 -> v (2-term, f32 head-split out). Tile 64x128.
// ---------------------------------------------------------------------------
__global__ __launch_bounds__(256) void proj_qkv(
    const float* __restrict__ q_in, const float* __restrict__ k_in,
    const float* __restrict__ v_in, const ushort* __restrict__ whi_all,
    const ushort* __restrict__ wlo_all, const float* __restrict__ bq,
    const float* __restrict__ bk, const float* __restrict__ bv,
    ushort* __restrict__ qhi, ushort* __restrict__ qlo,
    ushort* __restrict__ khi, ushort* __restrict__ klo,
    float* __restrict__ vstage)
{
    const int z = blockIdx.z;
    const float* X = (z == 0) ? q_in : (z == 1) ? k_in : v_in;
    const ushort* wth = whi_all + (size_t)z * FF * FF;
    const ushort* wtl = wlo_all + (size_t)z * FF * FF;
    const float* bias = (z == 0) ? bq : (z == 1) ? bk : bv;

    const int t  = threadIdx.x, w = t >> 6, l = t & 63;
    const int ar = l & 15, kg = (l >> 4) * 8;
    const int i0 = blockIdx.x * 64, j0 = blockIdx.y * 128;
    const int arow = i0 + w * 16 + ar;

    f32x4 acc[8];
    #pragma unroll
    for (int nt = 0; nt < 8; ++nt) acc[nt] = (f32x4){0.f, 0.f, 0.f, 0.f};

    for (int kk = 0; kk < FF; kk += 32) {
        const float* xr = X + (size_t)arow * FF + kk + kg;
        float4 f0 = *(const float4*)xr;
        float4 f1 = *(const float4*)(xr + 4);
        ushort h0 = f2bf_rne(f0.x), h1 = f2bf_rne(f0.y), h2 = f2bf_rne(f0.z), h3 = f2bf_rne(f0.w);
        ushort h4 = f2bf_rne(f1.x), h5 = f2bf_rne(f1.y), h6 = f2bf_rne(f1.z), h7 = f2bf_rne(f1.w);
        union { uint u[4]; bf16x8 v; } ah, al;
        ah.u[0] = (uint)h0 | ((uint)h1 << 16);
        ah.u[1] = (uint)h2 | ((uint)h3 << 16);
        ah.u[2] = (uint)h4 | ((uint)h5 << 16);
        ah.u[3] = (uint)h6 | ((uint)h7 << 16);
        if (z < 2) {
            al.u[0] = (uint)f2bf_rne(f0.x - bfval(h0)) | ((uint)f2bf_rne(f0.y - bfval(h1)) << 16);
            al.u[1] = (uint)f2bf_rne(f0.z - bfval(h2)) | ((uint)f2bf_rne(f0.w - bfval(h3)) << 16);
            al.u[2] = (uint)f2bf_rne(f1.x - bfval(h4)) | ((uint)f2bf_rne(f1.y - bfval(h5)) << 16);
            al.u[3] = (uint)f2bf_rne(f1.z - bfval(h6)) | ((uint)f2bf_rne(f1.w - bfval(h7)) << 16);
        }
        #pragma unroll
        for (int nt = 0; nt < 8; ++nt) {
            const size_t wo = (size_t)(j0 + nt * 16 + ar) * FF + kk + kg;
            bf16x8 bh = *(const bf16x8*)(wth + wo);
            bf16x8 bl = *(const bf16x8*)(wtl + wo);
            acc[nt] = MFMA16(ah.v, bh, acc[nt]);
            acc[nt] = MFMA16(ah.v, bl, acc[nt]);
            if (z < 2) acc[nt] = MFMA16(al.v, bh, acc[nt]);
        }
    }

    const int bidx = i0 / SS;
    ushort* ohi = (z == 0) ? qhi : khi;
    ushort* olo = (z == 0) ? qlo : klo;
    #pragma unroll
    for (int nt = 0; nt < 8; ++nt) {
        const int col = j0 + nt * 16 + ar;
        const float bb = bias[col];
        #pragma unroll
        for (int r = 0; r < 4; ++r) {
            const int rowl = w * 16 + (l >> 4) * 4 + r;
            const float val = acc[nt][r] + bb;
            const int s = (i0 - bidx * SS) + rowl;
            const size_t o = (((size_t)bidx * NH + (col >> 6)) * SS + s) * DD + (col & 63);
            if (z == 2) {
                vstage[o] = val;
            } else {
                ushort hv = f2bf_rne(val);
                ohi[o] = hv;
                olo[o] = f2bf_rne(val - bfval(hv));
            }
        }
    }
}

// ---------------------------------------------------------------------------
// Output projection: out = ctx @ wo + b (2-term, f32 out [row][FF])
// ---------------------------------------------------------------------------
__global__ __launch_bounds__(256) void proj_out(
    const float* __restrict__ X, const ushort* __restrict__ wth,
    const ushort* __restrict__ wtl, const float* __restrict__ bias,
    float* __restrict__ outf)
{
    const int t  = threadIdx.x, w = t >> 6, l = t & 63;
    const int ar = l & 15, kg = (l >> 4) * 8;
    const int i0 = blockIdx.x * 64, j0 = blockIdx.y * 128;
    const int arow = i0 + w * 16 + ar;

    f32x4 acc[8];
    #pragma unroll
    for (int nt = 0; nt < 8; ++nt) acc[nt] = (f32x4){0.f, 0.f, 0.f, 0.f};

    for (int kk = 0; kk < FF; kk += 32) {
        const float* xr = X + (size_t)arow * FF + kk + kg;
        float4 f0 = *(const float4*)xr;
        float4 f1 = *(const float4*)(xr + 4);
        union { uint u[4]; bf16x8 v; } ah;
        ah.u[0] = (uint)f2bf_rne(f0.x) | ((uint)f2bf_rne(f0.y) << 16);
        ah.u[1] = (uint)f2bf_rne(f0.z) | ((uint)f2bf_rne(f0.w) << 16);
        ah.u[2] = (uint)f2bf_rne(f1.x) | ((uint)f2bf_rne(f1.y) << 16);
        ah.u[3] = (uint)f2bf_rne(f1.z) | ((uint)f2bf_rne(f1.w) << 16);
        #pragma unroll
        for (int nt = 0; nt < 8; ++nt) {
            const size_t wo = (size_t)(j0 + nt * 16 + ar) * FF + kk + kg;
            bf16x8 bh = *(const bf16x8*)(wth + wo);
            bf16x8 bl = *(const bf16x8*)(wtl + wo);
            acc[nt] = MFMA16(ah.v, bh, acc[nt]);
            acc[nt] = MFMA16(ah.v, bl, acc[nt]);
        }
    }

    #pragma unroll
    for (int nt = 0; nt < 8; ++nt) {
        const int col = j0 + nt * 16 + ar;
        const float bb = bias[col];
        #pragma unroll
        for (int r = 0; r < 4; ++r) {
            const int rowl = w * 16 + (l >> 4) * 4 + r;
            outf[(size_t)(i0 + rowl) * FF + col] = acc[nt][r] + bb;
        }
    }
}

// ---------------------------------------------------------------------------
// Fused attention: per (q-tile 64, bh), 512 thr.
// Pass 1: 1-term QK (K-hi dbuf, 1 barrier/tile), m=0 exp-sum -> 1/Z.
// Pass 2: 3-term QK (K hi/lo dbuf) -> p -> per-wave LDS tile ->
//         NT attn stores + 2-term PV (V-hi dbuf). 1 barrier/tile.
// LDS 66KB -> 2 blocks/CU.
// ---------------------------------------------------------------------------
__global__ __launch_bounds__(512, 4) void fattn_kernel(
    const ushort* __restrict__ qhi, const ushort* __restrict__ qlo,
    const ushort* __restrict__ khi, const ushort* __restrict__ klo,
    const ushort* __restrict__ vthi,
    float* __restrict__ attn_out, float* __restrict__ ctx)
{
    __shared__ __align__(16) unsigned char smem[67584];
    ushort* KH0 = (ushort*)smem;          // [64][64] swizzled, dbuf
    ushort* KH1 = KH0 + 4096;
    ushort* KL0 = KH1 + 4096;
    ushort* KL1 = KL0 + 4096;
    ushort* VH0 = KL1 + 4096;             // [64 d][64 k] swizzled, dbuf
    ushort* VH1 = VH0 + 4096;
    float*  PT  = (float*)(VH1 + 4096);   // 8 waves x [16][36] f32 = 18432B
    float*  redS = PT;                    // pass-1 overlay [2][64]

    const int t = threadIdx.x, w = t >> 6, l = t & 63;
    const int ar = l & 15, kgi = l >> 4;
    const int kg = kgi * 8;
    const int qs = w & 3, kh = w >> 2;

    // XCD-chunked decode (grid 1152 = 8 XCDs x 144)
    const int xcd = blockIdx.x & 7;
    const int pos = blockIdx.x >> 3;
    const int bh  = xcd * 4 + (pos / 36);
    const int qt  = pos % 36;
    const int q0  = qt * 64;
    const int b   = bh >> 3, h = bh & 7;
    const size_t base = (size_t)bh * SS * DD;
    const float SC = 0.125f * 1.44269504f;

    // q fragments
    const size_t qo = base + (size_t)(q0 + qs * 16 + ar) * DD + kg;
    const bf16x8 qh0 = *(const bf16x8*)(qhi + qo);
    const bf16x8 qh1 = *(const bf16x8*)(qhi + qo + 32);
    const bf16x8 ql0 = *(const bf16x8*)(qlo + qo);
    const bf16x8 ql1 = *(const bf16x8*)(qlo + qo + 32);

    // staging addresses
    const int srow = t >> 3, sc8 = t & 7;
    const int sidx = srow * 64 + ((sc8 ^ (srow & 7)) << 3);
    const ushort* khsrc = khi + base + srow * 64 + sc8 * 8;
    const ushort* klsrc = klo + base + srow * 64 + sc8 * 8;
    const ushort* vhsrc = vthi + ((size_t)bh * DD + srow) * SS + sc8 * 8;

    // fragment read offsets (swizzled)
    const int sw  = ar & 7;
    const int i00 = kh * 2048 + ar * 64;
    const int i01 = i00 + 1024;
    const int s00 = (kgi ^ sw) << 3;
    const int s01 = ((4 | kgi) ^ sw) << 3;
    const int svw = ((kh * 4 + kgi) ^ sw) << 3;

    // ================= Pass 1: Z only (1-term, m=0) =================
    float s_[4] = {0.f, 0.f, 0.f, 0.f};
    {
        uint4 rk = *(const uint4*)khsrc;
        *(uint4*)&KH0[sidx] = rk;
        __syncthreads();
        for (int kt = 0; kt < 36; ++kt) {
            if (kt < 35) rk = *(const uint4*)(khsrc + (size_t)(kt + 1) * 4096);
            const ushort* KC = (kt & 1) ? KH1 : KH0;
            bf16x8 b00 = *(const bf16x8*)&KC[i00 + s00];
            bf16x8 b01 = *(const bf16x8*)&KC[i00 + s01];
            bf16x8 b10 = *(const bf16x8*)&KC[i01 + s00];
            bf16x8 b11 = *(const bf16x8*)&KC[i01 + s01];
            f32x4 a0 = {0.f,0.f,0.f,0.f}, a1 = {0.f,0.f,0.f,0.f};
            __builtin_amdgcn_s_setprio(1);
            a0 = MFMA16(qh0, b00, a0); a1 = MFMA16(qh0, b10, a1);
            a0 = MFMA16(qh1, b01, a0); a1 = MFMA16(qh1, b11, a1);
            __builtin_amdgcn_s_setprio(0);
            #pragma unroll
            for (int r = 0; r < 4; ++r)
                s_[r] += exp2f(a0[r] * SC) + exp2f(a1[r] * SC);
            if (kt < 35) {
                ushort* KN = (kt & 1) ? KH0 : KH1;
                *(uint4*)&KN[sidx] = rk;
            }
            __syncthreads();
        }
    }
    #pragma unroll
    for (int off = 1; off <= 8; off <<= 1) {
        #pragma unroll
        for (int r = 0; r < 4; ++r) s_[r] += __shfl_xor(s_[r], off);
    }
    if (ar == 0) {
        #pragma unroll
        for (int r = 0; r < 4; ++r)
            redS[kh * 64 + qs * 16 + kgi * 4 + r] = s_[r];
    }
    __syncthreads();
    float inv[4];
    #pragma unroll
    for (int r = 0; r < 4; ++r) {
        const int idx = qs * 16 + kgi * 4 + r;
        inv[r] = 1.0f / (redS[idx] + redS[64 + idx]);
    }

    // ================= Pass 2: emit + PV (1 barrier/tile) =================
    float* PTw = PT + w * 576;                    // [16][36]
    float* asto = attn_out + ((size_t)bh * SS + q0 + qs * 16 + (l >> 2)) * SS
                + kh * 32 + (l & 3) * 8;

    f32x4 acc[4];
    #pragma unroll
    for (int nt = 0; nt < 4; ++nt) acc[nt] = (f32x4){0.f, 0.f, 0.f, 0.f};

    {
        uint4 a = *(const uint4*)khsrc;
        uint4 bq = *(const uint4*)klsrc;
        uint4 c = *(const uint4*)vhsrc;
        *(uint4*)&KH0[sidx] = a;
        *(uint4*)&KL0[sidx] = bq;
        *(uint4*)&VH0[sidx] = c;
    }
    __syncthreads();

    for (int kt = 0; kt < 36; ++kt) {
        uint4 rkh, rkl, rvh;
        if (kt < 35) {
            rkh = *(const uint4*)(khsrc + (size_t)(kt + 1) * 4096);
            rkl = *(const uint4*)(klsrc + (size_t)(kt + 1) * 4096);
            rvh = *(const uint4*)(vhsrc + (size_t)(kt + 1) * 64);
        }
        const ushort* KHc = (kt & 1) ? KH1 : KH0;
        const ushort* KLc = (kt & 1) ? KL1 : KL0;
        const ushort* VHc = (kt & 1) ? VH1 : VH0;

        // ---- QK^T (3-term) ----
        bf16x8 bh00 = *(const bf16x8*)&KHc[i00 + s00];
        bf16x8 bh01 = *(const bf16x8*)&KHc[i00 + s01];
        bf16x8 bl00 = *(const bf16x8*)&KLc[i00 + s00];
        bf16x8 bl01 = *(const bf16x8*)&KLc[i00 + s01];
        bf16x8 bh10 = *(const bf16x8*)&KHc[i01 + s00];
        bf16x8 bh11 = *(const bf16x8*)&KHc[i01 + s01];
        bf16x8 bl10 = *(const bf16x8*)&KLc[i01 + s00];
        bf16x8 bl11 = *(const bf16x8*)&KLc[i01 + s01];
        f32x4 a0 = {0.f,0.f,0.f,0.f}, a1 = {0.f,0.f,0.f,0.f};
        __builtin_amdgcn_s_setprio(1);
        a0 = MFMA16(qh0, bh00, a0); a1 = MFMA16(qh0, bh10, a1);
        a0 = MFMA16(qh0, bl00, a0); a1 = MFMA16(qh0, bl10, a1);
        a0 = MFMA16(ql0, bh00, a0); a1 = MFMA16(ql0, bh10, a1);
        a0 = MFMA16(qh1, bh01, a0); a1 = MFMA16(qh1, bh11, a1);
        a0 = MFMA16(qh1, bl01, a0); a1 = MFMA16(qh1, bl11, a1);
        a0 = MFMA16(ql1, bh01, a0); a1 = MFMA16(ql1, bh11, a1);
        __builtin_amdgcn_s_setprio(0);

        // ---- softmax -> p into per-wave LDS tile ----
        #pragma unroll
        for (int r = 0; r < 4; ++r) {
            const int row = kgi * 4 + r;
            float p0 = exp2f(a0[r] * SC) * inv[r];
            float p1 = exp2f(a1[r] * SC) * inv[r];
            PTw[row * 36 + ar]      = p0;
            PTw[row * 36 + 16 + ar] = p1;
        }

        // ---- coalesced nontemporal attn store (transposed read) ----
        {
            const float* psr = PTw + (l >> 2) * 36 + (l & 3) * 8;
            f32x4 sv0 = *(const f32x4*)psr;
            f32x4 sv1 = *(const f32x4*)(psr + 4);
            f32x4* dst = (f32x4*)(asto + (size_t)kt * 64);
            __builtin_nontemporal_store(sv0, dst);
            __builtin_nontemporal_store(sv1, dst + 1);
        }

        // ---- PV (2-term: p_hi*v_hi + p_lo*v_hi) ----
        {
            const float* par = PTw + ar * 36 + kg;
            f32x4 pf0 = *(const f32x4*)par;
            f32x4 pf1 = *(const f32x4*)(par + 4);
            union { uint u[4]; bf16x8 v; } pah, pal;
            ushort hh[8]; float rr[8];
            #pragma unroll
            for (int j = 0; j < 4; ++j) {
                hh[j]     = f2bf_rne(pf0[j]); rr[j]     = pf0[j] - bfval(hh[j]);
                hh[4 + j] = f2bf_rne(pf1[j]); rr[4 + j] = pf1[j] - bfval(hh[4 + j]);
            }
            #pragma unroll
            for (int j = 0; j < 4; ++j) {
                pah.u[j] = (uint)hh[2*j] | ((uint)hh[2*j+1] << 16);
                pal.u[j] = (uint)f2bf_rne(rr[2*j]) | ((uint)f2bf_rne(rr[2*j+1]) << 16);
            }
            __builtin_amdgcn_s_setprio(1);
            #pragma unroll
            for (int nt = 0; nt < 4; ++nt) {
                const int vfi = (nt * 16 + ar) * 64 + svw;
                bf16x8 vh = *(const bf16x8*)&VHc[vfi];
                acc[nt] = MFMA16(pah.v, vh, acc[nt]);
                acc[nt] = MFMA16(pal.v, vh, acc[nt]);
            }
            __builtin_amdgcn_s_setprio(0);
        }

        // stage next tile into the other buffers (no hazard pre-barrier)
        if (kt < 35) {
            ushort* KHN = (kt & 1) ? KH0 : KH1;
            ushort* KLN = (kt & 1) ? KL0 : KL1;
            ushort* VHN = (kt & 1) ? VH0 : VH1;
            *(uint4*)&KHN[sidx] = rkh;
            *(uint4*)&KLN[sidx] = rkl;
            *(uint4*)&VHN[sidx] = rvh;
        }
        __syncthreads();
    }

    // ---- cross-wave ctx reduction (kh pairs) ----
    float* SCR = (float*)smem;           // [8][16][68] = 34,816B
    #pragma unroll
    for (int nt = 0; nt < 4; ++nt) {
        #pragma unroll
        for (int r = 0; r < 4; ++r)
            SCR[w * 1088 + (kgi * 4 + r) * 68 + nt * 16 + ar] = acc[nt][r];
    }
    __syncthreads();
    {
        const int rrow = t >> 3;
        const int dg   = (t & 7) * 8;
        const int rqs  = rrow >> 4, rl = rrow & 15;
        const float* s0p = SCR + rqs * 1088 + rl * 68 + dg;
        const float* s1p = s0p + 4 * 1088;
        f32x4 o0, o1;
        #pragma unroll
        for (int j = 0; j < 4; ++j) o0[j] = s0p[j] + s1p[j];
        #pragma unroll
        for (int j = 0; j < 4; ++j) o1[j] = s0p[4 + j] + s1p[4 + j];
        float* cdst = ctx + ((size_t)b * SS + q0 + rrow) * FF + h * DD + dg;
        *(f32x4*)cdst = o0;
        *(f32x4*)(cdst + 4) = o1;
    }
}

extern "C" void kernel_launch(void* const* d_in, const int* in_sizes, int n_in,
                              void* d_out, int out_size, void* d_ws, size_t ws_size,
                              hipStream_t stream) {
    (void)in_sizes; (void)n_in; (void)out_size; (void)ws_size;
    const float* query = (const float*)d_in[0];
    const float* value = (const float*)d_in[1];
    const float* keys  = (const float*)d_in[2];
    const float* wq_w  = (const float*)d_in[3];
    const float* wq_b  = (const float*)d_in[4];
    const float* wk_w  = (const float*)d_in[5];
    const float* wk_b  = (const float*)d_in[6];
    const float* wv_w  = (const float*)d_in[7];
    const float* wv_b  = (const float*)d_in[8];
    const float* wo_w  = (const float*)d_in[9];
    const float* wo_b  = (const float*)d_in[10];

    float* out  = (float*)d_out;
    float* attn = out + (size_t)BB * SS * FF;

    const size_t NQ = (size_t)BB * NH * SS * DD;   // 4,718,592
    ushort* qhi    = (ushort*)d_ws;
    ushort* qlo    = qhi + NQ;
    ushort* khi    = qlo + NQ;
    ushort* klo    = khi + NQ;
    ushort* vthi   = klo + NQ;
    float*  vstage = (float*)(vthi + NQ);          // NQ f32; later ctx
    ushort* wthi   = (ushort*)(vstage + NQ);       // 4 x FF*FF
    ushort* wtlo   = wthi + (size_t)4 * FF * FF;

    dim3 gwt(FF / 64, FF / 64, 4);
    dim3 gqkv(BSR / 64, FF / 128, 3);
    dim3 gproj(BSR / 64, FF / 128);
    dim3 gvt(SS / 64, BB * NH);

    wtsplit_all<<<gwt, 256, 0, stream>>>(wq_w, wk_w, wv_w, wo_w, wthi, wtlo);
    proj_qkv<<<gqkv, 256, 0, stream>>>(query, keys, value, wthi, wtlo,
                                       wq_b, wk_b, wv_b,
                                       qhi, qlo, khi, klo, vstage);
    vtsplit_kernel<<<gvt, 256, 0, stream>>>(vstage, vthi);

    fattn_kernel<<<36 * 32, 512, 0, stream>>>(qhi, qlo, khi, klo, vthi,
                                              attn, vstage);

    proj_out<<<gproj, 256, 0, stream>>>(vstage, wthi + (size_t)3 * FF * FF,
                                        wtlo + (size_t)3 * FF * FF, wo_b, out);
}

// Round 8
// 603.105 us; speedup vs baseline: 2.1469x; 1.0616x over previous
//
#include <hip/hip_runtime.h>
#include <cstddef>

#define BB 4
#define SS 2304      // 48*48
#define FF 512
#define NH 8
#define DD 64
#define BSR (BB*SS)  // 9216 rows

typedef __attribute__((ext_vector_type(8))) short bf16x8;
typedef __attribute__((ext_vector_type(4))) float f32x4;
#define MFMA16(a,b,c) __builtin_amdgcn_mfma_f32_16x16x32_bf16((a),(b),(c),0,0,0)

__device__ __forceinline__ ushort f2bf_rne(float x) {
    uint u = __float_as_uint(x);
    uint r = u + 0x7fffu + ((u >> 16) & 1u);
    return (ushort)(r >> 16);
}
__device__ __forceinline__ float bfval(ushort h) {
    return __uint_as_float((uint)h << 16);
}
// packed bf16 convert: dst.lo16 = bf16(a), dst.hi16 = bf16(b)  (RNE)
__device__ __forceinline__ uint cvt_pk_bf16(float a, float b) {
    uint r;
    asm("v_cvt_pk_bf16_f32 %0, %1, %2" : "=v"(r) : "v"(a), "v"(b));
    return r;
}
__device__ __forceinline__ float lo16val(uint p) { return __uint_as_float(p << 16); }
__device__ __forceinline__ float hi16val(uint p) { return __uint_as_float(p & 0xffff0000u); }

// ---------------------------------------------------------------------------
// All 4 weight transpose+splits: W[k][n] -> Wt{hi,lo}[n][k] bf16 (z selects)
// ---------------------------------------------------------------------------
__global__ __launch_bounds__(256) void wtsplit_all(
    const float* __restrict__ w0, const float* __restrict__ w1,
    const float* __restrict__ w2, const float* __restrict__ w3,
    ushort* __restrict__ whi_all, ushort* __restrict__ wlo_all)
{
    __shared__ __align__(16) float tile[64][68];
    const int z = blockIdx.z;
    const float* w = (z == 0) ? w0 : (z == 1) ? w1 : (z == 2) ? w2 : w3;
    ushort* whi = whi_all + (size_t)z * FF * FF;
    ushort* wlo = wlo_all + (size_t)z * FF * FF;

    const int t  = threadIdx.x;
    const int kt = blockIdx.x;
    const int nt = blockIdx.y;
    {
        const int r  = t >> 2;
        const int cg = (t & 3) * 16;
        const float* src = w + (size_t)(kt * 64 + r) * FF + nt * 64 + cg;
        #pragma unroll
        for (int j = 0; j < 4; ++j)
            *(float4*)&tile[r][cg + 4 * j] = *(const float4*)(src + 4 * j);
    }
    __syncthreads();
    {
        const int n  = t >> 2;
        const int kg = (t & 3) * 16;
        uint H[8], L[8];
        #pragma unroll
        for (int j = 0; j < 8; ++j) {
            float x0 = tile[kg + 2 * j][n];
            float x1 = tile[kg + 2 * j + 1][n];
            uint hp = cvt_pk_bf16(x0, x1);
            H[j] = hp;
            L[j] = cvt_pk_bf16(x0 - lo16val(hp), x1 - hi16val(hp));
        }
        size_t off = (size_t)(nt * 64 + n) * FF + kt * 64 + kg;
        *(uint4*)(whi + off)     = make_uint4(H[0], H[1], H[2], H[3]);
        *(uint4*)(whi + off + 8) = make_uint4(H[4], H[5], H[6], H[7]);
        *(uint4*)(wlo + off)     = make_uint4(L[0], L[1], L[2], L[3]);
        *(uint4*)(wlo + off + 8) = make_uint4(L[4], L[5], L[6], L[7]);
    }
}

// ---------------------------------------------------------------------------
// Fused QKV projection, tile 64x128: z=0 q (3-term, hi/lo), z=1 k (3-term,
// hi/lo), z=2 v (2-term, bf16-transposed [bh][d][s] direct).
// Epilogue bounces through LDS for coalesced wide stores.
// ---------------------------------------------------------------------------
__global__ __launch_bounds__(256) void proj_qkv(
    const float* __restrict__ q_in, const float* __restrict__ k_in,
    const float* __restrict__ v_in, const ushort* __restrict__ whi_all,
    const ushort* __restrict__ wlo_all, const float* __restrict__ bq,
    const float* __restrict__ bk, const float* __restrict__ bv,
    ushort* __restrict__ qhi, ushort* __restrict__ qlo,
    ushort* __restrict__ khi, ushort* __restrict__ klo,
    ushort* __restrict__ vthi)
{
    __shared__ __align__(16) ushort TL[9216];   // 18,432 B

    const int z = blockIdx.z;
    const float* X = (z == 0) ? q_in : (z == 1) ? k_in : v_in;
    const ushort* wth = whi_all + (size_t)z * FF * FF;
    const ushort* wtl = wlo_all + (size_t)z * FF * FF;
    const float* bias = (z == 0) ? bq : (z == 1) ? bk : bv;

    const int t  = threadIdx.x, w = t >> 6, l = t & 63;
    const int ar = l & 15, kg = (l >> 4) * 8;
    const int i0 = blockIdx.x * 64, j0 = blockIdx.y * 128;
    const int arow = i0 + w * 16 + ar;

    f32x4 acc[8];
    #pragma unroll
    for (int nt = 0; nt < 8; ++nt) acc[nt] = (f32x4){0.f, 0.f, 0.f, 0.f};

    for (int kk = 0; kk < FF; kk += 32) {
        const float* xr = X + (size_t)arow * FF + kk + kg;
        float4 f0 = *(const float4*)xr;
        float4 f1 = *(const float4*)(xr + 4);
        union { uint u[4]; bf16x8 v; } ah, al;
        ah.u[0] = cvt_pk_bf16(f0.x, f0.y);
        ah.u[1] = cvt_pk_bf16(f0.z, f0.w);
        ah.u[2] = cvt_pk_bf16(f1.x, f1.y);
        ah.u[3] = cvt_pk_bf16(f1.z, f1.w);
        if (z < 2) {
            al.u[0] = cvt_pk_bf16(f0.x - lo16val(ah.u[0]), f0.y - hi16val(ah.u[0]));
            al.u[1] = cvt_pk_bf16(f0.z - lo16val(ah.u[1]), f0.w - hi16val(ah.u[1]));
            al.u[2] = cvt_pk_bf16(f1.x - lo16val(ah.u[2]), f1.y - hi16val(ah.u[2]));
            al.u[3] = cvt_pk_bf16(f1.z - lo16val(ah.u[3]), f1.w - hi16val(ah.u[3]));
        }
        #pragma unroll
        for (int nt = 0; nt < 8; ++nt) {
            const size_t wo = (size_t)(j0 + nt * 16 + ar) * FF + kk + kg;
            bf16x8 bh = *(const bf16x8*)(wth + wo);
            bf16x8 bl = *(const bf16x8*)(wtl + wo);
            acc[nt] = MFMA16(ah.v, bh, acc[nt]);
            acc[nt] = MFMA16(ah.v, bl, acc[nt]);
            if (z < 2) acc[nt] = MFMA16(al.v, bh, acc[nt]);
        }
    }

    const int bidx = i0 / SS;
    const int s0b  = i0 - bidx * SS;
    const int rowl = w * 16 + ((l >> 4) << 2);

    if (z == 2) {
        // transposed tile [col 128][row 64] -> vthi[bh][d][s]
        #pragma unroll
        for (int nt = 0; nt < 8; ++nt) {
            const float bb = bias[j0 + nt * 16 + ar];
            #pragma unroll
            for (int r = 0; r < 4; ++r)
                TL[(nt * 16 + ar) * 72 + rowl + r] = f2bf_rne(acc[nt][r] + bb);
        }
        __syncthreads();
        const int d = t >> 1, hf = t & 1;
        const ushort* src = &TL[d * 72 + hf * 32];
        const size_t o = (((size_t)bidx * NH + ((j0 + d) >> 6)) * DD + (d & 63)) * SS
                       + s0b + hf * 32;
        *(uint4*)(vthi + o)      = *(const uint4*)(src);
        *(uint4*)(vthi + o + 8)  = *(const uint4*)(src + 8);
        *(uint4*)(vthi + o + 16) = *(const uint4*)(src + 16);
        *(uint4*)(vthi + o + 24) = *(const uint4*)(src + 24);
    } else {
        ushort* ohi = (z == 0) ? qhi : khi;
        ushort* olo = (z == 0) ? qlo : klo;
        const int rowf = t >> 2, qd = t & 3;
        const int colg = j0 + qd * 32;
        const size_t o = (((size_t)bidx * NH + (colg >> 6)) * SS + s0b + rowf) * DD
                       + (colg & 63);
        // hi tile
        #pragma unroll
        for (int nt = 0; nt < 8; ++nt) {
            const float bb = bias[j0 + nt * 16 + ar];
            #pragma unroll
            for (int r = 0; r < 4; ++r)
                TL[(rowl + r) * 136 + nt * 16 + ar] = f2bf_rne(acc[nt][r] + bb);
        }
        __syncthreads();
        {
            const ushort* src = &TL[rowf * 136 + qd * 32];
            *(uint4*)(ohi + o)      = *(const uint4*)(src);
            *(uint4*)(ohi + o + 8)  = *(const uint4*)(src + 8);
            *(uint4*)(ohi + o + 16) = *(const uint4*)(src + 16);
            *(uint4*)(ohi + o + 24) = *(const uint4*)(src + 24);
        }
        __syncthreads();
        // lo tile
        #pragma unroll
        for (int nt = 0; nt < 8; ++nt) {
            const float bb = bias[j0 + nt * 16 + ar];
            #pragma unroll
            for (int r = 0; r < 4; ++r) {
                const float val = acc[nt][r] + bb;
                const ushort hv = f2bf_rne(val);
                TL[(rowl + r) * 136 + nt * 16 + ar] = f2bf_rne(val - bfval(hv));
            }
        }
        __syncthreads();
        {
            const ushort* src = &TL[rowf * 136 + qd * 32];
            *(uint4*)(olo + o)      = *(const uint4*)(src);
            *(uint4*)(olo + o + 8)  = *(const uint4*)(src + 8);
            *(uint4*)(olo + o + 16) = *(const uint4*)(src + 16);
            *(uint4*)(olo + o + 24) = *(const uint4*)(src + 24);
        }
    }
}

// ---------------------------------------------------------------------------
// Output projection: out = ctx @ wo + b (2-term, f32 out [row][FF])
// ---------------------------------------------------------------------------
__global__ __launch_bounds__(256) void proj_out(
    const float* __restrict__ X, const ushort* __restrict__ wth,
    const ushort* __restrict__ wtl, const float* __restrict__ bias,
    float* __restrict__ outf)
{
    const int t  = threadIdx.x, w = t >> 6, l = t & 63;
    const int ar = l & 15, kg = (l >> 4) * 8;
    const int i0 = blockIdx.x * 64, j0 = blockIdx.y * 128;
    const int arow = i0 + w * 16 + ar;

    f32x4 acc[8];
    #pragma unroll
    for (int nt = 0; nt < 8; ++nt) acc[nt] = (f32x4){0.f, 0.f, 0.f, 0.f};

    for (int kk = 0; kk < FF; kk += 32) {
        const float* xr = X + (size_t)arow * FF + kk + kg;
        float4 f0 = *(const float4*)xr;
        float4 f1 = *(const float4*)(xr + 4);
        union { uint u[4]; bf16x8 v; } ah;
        ah.u[0] = cvt_pk_bf16(f0.x, f0.y);
        ah.u[1] = cvt_pk_bf16(f0.z, f0.w);
        ah.u[2] = cvt_pk_bf16(f1.x, f1.y);
        ah.u[3] = cvt_pk_bf16(f1.z, f1.w);
        #pragma unroll
        for (int nt = 0; nt < 8; ++nt) {
            const size_t wo = (size_t)(j0 + nt * 16 + ar) * FF + kk + kg;
            bf16x8 bh = *(const bf16x8*)(wth + wo);
            bf16x8 bl = *(const bf16x8*)(wtl + wo);
            acc[nt] = MFMA16(ah.v, bh, acc[nt]);
            acc[nt] = MFMA16(ah.v, bl, acc[nt]);
        }
    }

    #pragma unroll
    for (int nt = 0; nt < 8; ++nt) {
        const int col = j0 + nt * 16 + ar;
        const float bb = bias[col];
        #pragma unroll
        for (int r = 0; r < 4; ++r) {
            const int rowl = w * 16 + (l >> 4) * 4 + r;
            outf[(size_t)(i0 + rowl) * FF + col] = acc[nt][r] + bb;
        }
    }
}

// ---------------------------------------------------------------------------
// Fused attention: per (q-tile 64, bh), 512 thr.
// Pass 1: 1-term QK (K-hi dbuf), exp-sum -> -log2(Z).
// Pass 2: 3-term QK (K hi/lo dbuf) -> p=exp2(fma) -> per-wave LDS tile ->
//         NT attn stores + 2-term PV (V-hi dbuf). 1 barrier/tile.
// ---------------------------------------------------------------------------
__global__ __launch_bounds__(512, 4) void fattn_kernel(
    const ushort* __restrict__ qhi, const ushort* __restrict__ qlo,
    const ushort* __restrict__ khi, const ushort* __restrict__ klo,
    const ushort* __restrict__ vthi,
    float* __restrict__ attn_out, float* __restrict__ ctx)
{
    __shared__ __align__(16) unsigned char smem[67584];
    ushort* KH0 = (ushort*)smem;          // [64][64] swizzled, dbuf
    ushort* KH1 = KH0 + 4096;
    ushort* KL0 = KH1 + 4096;
    ushort* KL1 = KL0 + 4096;
    ushort* VH0 = KL1 + 4096;             // [64 d][64 k] swizzled, dbuf
    ushort* VH1 = VH0 + 4096;
    float*  PT  = (float*)(VH1 + 4096);   // 8 waves x [16][36] f32
    float*  redS = PT;                    // pass-1 overlay [2][64]

    const int t = threadIdx.x, w = t >> 6, l = t & 63;
    const int ar = l & 15, kgi = l >> 4;
    const int kg = kgi * 8;
    const int qs = w & 3, kh = w >> 2;

    // XCD-chunked decode (grid 1152 = 8 XCDs x 144)
    const int xcd = blockIdx.x & 7;
    const int pos = blockIdx.x >> 3;
    const int bh  = xcd * 4 + (pos / 36);
    const int qt  = pos % 36;
    const int q0  = qt * 64;
    const int b   = bh >> 3, h = bh & 7;
    const size_t base = (size_t)bh * SS * DD;
    const float SC = 0.125f * 1.44269504f;

    // q fragments
    const size_t qo = base + (size_t)(q0 + qs * 16 + ar) * DD + kg;
    const bf16x8 qh0 = *(const bf16x8*)(qhi + qo);
    const bf16x8 qh1 = *(const bf16x8*)(qhi + qo + 32);
    const bf16x8 ql0 = *(const bf16x8*)(qlo + qo);
    const bf16x8 ql1 = *(const bf16x8*)(qlo + qo + 32);

    // staging addresses
    const int srow = t >> 3, sc8 = t & 7;
    const int sidx = srow * 64 + ((sc8 ^ (srow & 7)) << 3);
    const ushort* khsrc = khi + base + srow * 64 + sc8 * 8;
    const ushort* klsrc = klo + base + srow * 64 + sc8 * 8;
    const ushort* vhsrc = vthi + ((size_t)bh * DD + srow) * SS + sc8 * 8;

    // fragment read offsets (swizzled)
    const int sw  = ar & 7;
    const int i00 = kh * 2048 + ar * 64;
    const int i01 = i00 + 1024;
    const int s00 = (kgi ^ sw) << 3;
    const int s01 = ((4 | kgi) ^ sw) << 3;
    const int svw = ((kh * 4 + kgi) ^ sw) << 3;

    // ================= Pass 1: Z only (1-term, m=0) =================
    float s_[4] = {0.f, 0.f, 0.f, 0.f};
    {
        uint4 rk = *(const uint4*)khsrc;
        *(uint4*)&KH0[sidx] = rk;
        __syncthreads();
        for (int kt = 0; kt < 36; ++kt) {
            if (kt < 35) rk = *(const uint4*)(khsrc + (size_t)(kt + 1) * 4096);
            const ushort* KC = (kt & 1) ? KH1 : KH0;
            bf16x8 b00 = *(const bf16x8*)&KC[i00 + s00];
            bf16x8 b01 = *(const bf16x8*)&KC[i00 + s01];
            bf16x8 b10 = *(const bf16x8*)&KC[i01 + s00];
            bf16x8 b11 = *(const bf16x8*)&KC[i01 + s01];
            f32x4 a0 = {0.f,0.f,0.f,0.f}, a1 = {0.f,0.f,0.f,0.f};
            __builtin_amdgcn_s_setprio(1);
            a0 = MFMA16(qh0, b00, a0); a1 = MFMA16(qh0, b10, a1);
            a0 = MFMA16(qh1, b01, a0); a1 = MFMA16(qh1, b11, a1);
            __builtin_amdgcn_s_setprio(0);
            #pragma unroll
            for (int r = 0; r < 4; ++r)
                s_[r] += exp2f(a0[r] * SC) + exp2f(a1[r] * SC);
            if (kt < 35) {
                ushort* KN = (kt & 1) ? KH0 : KH1;
                *(uint4*)&KN[sidx] = rk;
            }
            __syncthreads();
        }
    }
    #pragma unroll
    for (int off = 1; off <= 8; off <<= 1) {
        #pragma unroll
        for (int r = 0; r < 4; ++r) s_[r] += __shfl_xor(s_[r], off);
    }
    if (ar == 0) {
        #pragma unroll
        for (int r = 0; r < 4; ++r)
            redS[kh * 64 + qs * 16 + kgi * 4 + r] = s_[r];
    }
    __syncthreads();
    float linv[4];
    #pragma unroll
    for (int r = 0; r < 4; ++r) {
        const int idx = qs * 16 + kgi * 4 + r;
        linv[r] = -__log2f(redS[idx] + redS[64 + idx]);
    }

    // ================= Pass 2: emit + PV (1 barrier/tile) =================
    float* PTw = PT + w * 576;                    // [16][36]
    float* asto = attn_out + ((size_t)bh * SS + q0 + qs * 16 + (l >> 2)) * SS
                + kh * 32 + (l & 3) * 8;

    f32x4 acc[4];
    #pragma unroll
    for (int nt = 0; nt < 4; ++nt) acc[nt] = (f32x4){0.f, 0.f, 0.f, 0.f};

    {
        uint4 a = *(const uint4*)khsrc;
        uint4 bq = *(const uint4*)klsrc;
        uint4 c = *(const uint4*)vhsrc;
        *(uint4*)&KH0[sidx] = a;
        *(uint4*)&KL0[sidx] = bq;
        *(uint4*)&VH0[sidx] = c;
    }
    __syncthreads();

    for (int kt = 0; kt < 36; ++kt) {
        uint4 rkh, rkl, rvh;
        if (kt < 35) {
            rkh = *(const uint4*)(khsrc + (size_t)(kt + 1) * 4096);
            rkl = *(const uint4*)(klsrc + (size_t)(kt + 1) * 4096);
            rvh = *(const uint4*)(vhsrc + (size_t)(kt + 1) * 64);
        }
        const ushort* KHc = (kt & 1) ? KH1 : KH0;
        const ushort* KLc = (kt & 1) ? KL1 : KL0;
        const ushort* VHc = (kt & 1) ? VH1 : VH0;

        // ---- QK^T (3-term) ----
        bf16x8 bh00 = *(const bf16x8*)&KHc[i00 + s00];
        bf16x8 bh01 = *(const bf16x8*)&KHc[i00 + s01];
        bf16x8 bl00 = *(const bf16x8*)&KLc[i00 + s00];
        bf16x8 bl01 = *(const bf16x8*)&KLc[i00 + s01];
        bf16x8 bh10 = *(const bf16x8*)&KHc[i01 + s00];
        bf16x8 bh11 = *(const bf16x8*)&KHc[i01 + s01];
        bf16x8 bl10 = *(const bf16x8*)&KLc[i01 + s00];
        bf16x8 bl11 = *(const bf16x8*)&KLc[i01 + s01];
        f32x4 a0 = {0.f,0.f,0.f,0.f}, a1 = {0.f,0.f,0.f,0.f};
        __builtin_amdgcn_s_setprio(1);
        a0 = MFMA16(qh0, bh00, a0); a1 = MFMA16(qh0, bh10, a1);
        a0 = MFMA16(qh0, bl00, a0); a1 = MFMA16(qh0, bl10, a1);
        a0 = MFMA16(ql0, bh00, a0); a1 = MFMA16(ql0, bh10, a1);
        a0 = MFMA16(qh1, bh01, a0); a1 = MFMA16(qh1, bh11, a1);
        a0 = MFMA16(qh1, bl01, a0); a1 = MFMA16(qh1, bl11, a1);
        a0 = MFMA16(ql1, bh01, a0); a1 = MFMA16(ql1, bh11, a1);
        __builtin_amdgcn_s_setprio(0);

        // ---- p = exp2(fma(a,SC,-log2 Z)) -> per-wave LDS tile ----
        #pragma unroll
        for (int r = 0; r < 4; ++r) {
            const int row = kgi * 4 + r;
            float p0 = exp2f(fmaf(a0[r], SC, linv[r]));
            float p1 = exp2f(fmaf(a1[r], SC, linv[r]));
            PTw[row * 36 + ar]      = p0;
            PTw[row * 36 + 16 + ar] = p1;
        }

        // ---- coalesced nontemporal attn store (transposed read) ----
        {
            const float* psr = PTw + (l >> 2) * 36 + (l & 3) * 8;
            f32x4 sv0 = *(const f32x4*)psr;
            f32x4 sv1 = *(const f32x4*)(psr + 4);
            f32x4* dst = (f32x4*)(asto + (size_t)kt * 64);
            __builtin_nontemporal_store(sv0, dst);
            __builtin_nontemporal_store(sv1, dst + 1);
        }

        // ---- PV (2-term: p_hi*v_hi + p_lo*v_hi), cvt_pk pack ----
        {
            const float* par = PTw + ar * 36 + kg;
            f32x4 pf0 = *(const f32x4*)par;
            f32x4 pf1 = *(const f32x4*)(par + 4);
            union { uint u[4]; bf16x8 v; } pah, pal;
            pah.u[0] = cvt_pk_bf16(pf0[0], pf0[1]);
            pah.u[1] = cvt_pk_bf16(pf0[2], pf0[3]);
            pah.u[2] = cvt_pk_bf16(pf1[0], pf1[1]);
            pah.u[3] = cvt_pk_bf16(pf1[2], pf1[3]);
            pal.u[0] = cvt_pk_bf16(pf0[0] - lo16val(pah.u[0]), pf0[1] - hi16val(pah.u[0]));
            pal.u[1] = cvt_pk_bf16(pf0[2] - lo16val(pah.u[1]), pf0[3] - hi16val(pah.u[1]));
            pal.u[2] = cvt_pk_bf16(pf1[0] - lo16val(pah.u[2]), pf1[1] - hi16val(pah.u[2]));
            pal.u[3] = cvt_pk_bf16(pf1[2] - lo16val(pah.u[3]), pf1[3] - hi16val(pah.u[3]));
            __builtin_amdgcn_s_setprio(1);
            #pragma unroll
            for (int nt = 0; nt < 4; ++nt) {
                const int vfi = (nt * 16 + ar) * 64 + svw;
                bf16x8 vh = *(const bf16x8*)&VHc[vfi];
                acc[nt] = MFMA16(pah.v, vh, acc[nt]);
                acc[nt] = MFMA16(pal.v, vh, acc[nt]);
            }
            __builtin_amdgcn_s_setprio(0);
        }

        // stage next tile into the other buffers
        if (kt < 35) {
            ushort* KHN = (kt & 1) ? KH0 : KH1;
            ushort* KLN = (kt & 1) ? KL0 : KL1;
            ushort* VHN = (kt & 1) ? VH0 : VH1;
            *(uint4*)&KHN[sidx] = rkh;
            *(uint4*)&KLN[sidx] = rkl;
            *(uint4*)&VHN[sidx] = rvh;
        }
        __syncthreads();
    }

    // ---- cross-wave ctx reduction (kh pairs) ----
    float* SCR = (float*)smem;           // [8][16][68]
    #pragma unroll
    for (int nt = 0; nt < 4; ++nt) {
        #pragma unroll
        for (int r = 0; r < 4; ++r)
            SCR[w * 1088 + (kgi * 4 + r) * 68 + nt * 16 + ar] = acc[nt][r];
    }
    __syncthreads();
    {
        const int rrow = t >> 3;
        const int dg   = (t & 7) * 8;
        const int rqs  = rrow >> 4, rl = rrow & 15;
        const float* s0p = SCR + rqs * 1088 + rl * 68 + dg;
        const float* s1p = s0p + 4 * 1088;
        f32x4 o0, o1;
        #pragma unroll
        for (int j = 0; j < 4; ++j) o0[j] = s0p[j] + s1p[j];
        #pragma unroll
        for (int j = 0; j < 4; ++j) o1[j] = s0p[4 + j] + s1p[4 + j];
        float* cdst = ctx + ((size_t)b * SS + q0 + rrow) * FF + h * DD + dg;
        *(f32x4*)cdst = o0;
        *(f32x4*)(cdst + 4) = o1;
    }
}

extern "C" void kernel_launch(void* const* d_in, const int* in_sizes, int n_in,
                              void* d_out, int out_size, void* d_ws, size_t ws_size,
                              hipStream_t stream) {
    (void)in_sizes; (void)n_in; (void)out_size; (void)ws_size;
    const float* query = (const float*)d_in[0];
    const float* value = (const float*)d_in[1];
    const float* keys  = (const float*)d_in[2];
    const float* wq_w  = (const float*)d_in[3];
    const float* wq_b  = (const float*)d_in[4];
    const float* wk_w  = (const float*)d_in[5];
    const float* wk_b  = (const float*)d_in[6];
    const float* wv_w  = (const float*)d_in[7];
    const float* wv_b  = (const float*)d_in[8];
    const float* wo_w  = (const float*)d_in[9];
    const float* wo_b  = (const float*)d_in[10];

    float* out  = (float*)d_out;
    float* attn = out + (size_t)BB * SS * FF;

    const size_t NQ = (size_t)BB * NH * SS * DD;   // 4,718,592
    ushort* qhi    = (ushort*)d_ws;
    ushort* qlo    = qhi + NQ;
    ushort* khi    = qlo + NQ;
    ushort* klo    = khi + NQ;
    ushort* vthi   = klo + NQ;
    float*  vstage = (float*)(vthi + NQ);          // ctx buffer
    ushort* wthi   = (ushort*)(vstage + NQ);       // 4 x FF*FF
    ushort* wtlo   = wthi + (size_t)4 * FF * FF;

    dim3 gwt(FF / 64, FF / 64, 4);
    dim3 gqkv(BSR / 64, FF / 128, 3);
    dim3 gproj(BSR / 64, FF / 128);

    wtsplit_all<<<gwt, 256, 0, stream>>>(wq_w, wk_w, wv_w, wo_w, wthi, wtlo);
    proj_qkv<<<gqkv, 256, 0, stream>>>(query, keys, value, wthi, wtlo,
                                       wq_b, wk_b, wv_b,
                                       qhi, qlo, khi, klo, vthi);

    fattn_kernel<<<36 * 32, 512, 0, stream>>>(qhi, qlo, khi, klo, vthi,
                                              attn, vstage);

    proj_out<<<gproj, 256, 0, stream>>>(vstage, wthi + (size_t)3 * FF * FF,
                                        wtlo + (size_t)3 * FF * FF, wo_b, out);
}